// Round 12
// baseline (571.384 us; speedup 1.0000x reference)
//
#include <hip/hip_runtime.h>
#include <hip/hip_bf16.h>
#include <hip/hip_fp16.h>
#include <math.h>

#define NN 50000
#define NE 400000
#define INDIM 128
#define HID 64
#define HC 256
#define NL 6
#define ED 16
#define SCAN_B 256
#define SCAN_NB ((NN + SCAN_B - 1)/SCAN_B)   // 196
#define NBIN 64
#define BINPAD 16

typedef __attribute__((ext_vector_type(8))) short short8;
typedef __attribute__((ext_vector_type(4))) float f32x4;
typedef _Float16 h2 __attribute__((ext_vector_type(2)));

static __device__ __forceinline__ float4 ld4(const float* p){ return *(const float4*)p; }
static __device__ __forceinline__ unsigned short f2b(float x){
  __hip_bfloat16 h = __float2bfloat16(x);
  return *(unsigned short*)&h;
}
static __device__ __forceinline__ unsigned short f2h(float x){
  __half h = __float2half(x);
  return *(unsigned short*)&h;
}
static __device__ __forceinline__ h2 bch(unsigned u){ return __builtin_bit_cast(h2, u); }
static __device__ __forceinline__ h2 hab(h2 x){
  return __builtin_bit_cast(h2, __builtin_bit_cast(unsigned, x) & 0x7FFF7FFFu);
}

// DPP lane combine (pure VALU): 0xB1=xor1(quad), 0x4E=xor2(quad), 0x141=row_half_mirror, 0x128=row_ror:8
#define DPP_ADD(X, CTRL) \
  ((X) + __builtin_bit_cast(float, __builtin_amdgcn_update_dpp(0, __builtin_bit_cast(int, (X)), (CTRL), 0xF, 0xF, true)))

// ---------------- prep: bf16 weights + Wl/Wr fusion + ep_table ----------------
__global__ void prep_kernel(const float* __restrict__ inW, const float* __restrict__ Wl,
                            const float* __restrict__ Wr, const float* __restrict__ bl,
                            const float* __restrict__ br, const float* __restrict__ etab,
                            const float* __restrict__ We,
                            unsigned short* __restrict__ inW_bf,
                            unsigned short* __restrict__ Wlr,
                            float* __restrict__ blr, float* __restrict__ ep){
  int i = blockIdx.x*blockDim.x + threadIdx.x;
  if (i < HID*INDIM) inW_bf[i] = f2b(inW[i]);
  if (i < NL*512){
    int l = i / 512, c = i % 512;
    blr[i] = (c < HC) ? bl[l*HC + c] : br[l*HC + (c-HC)];
  }
  if (i < NL*3*HC){
    int l  = i / (3*HC);
    int a  = (i / HC) % 3;
    int hc = i % HC;
    const float* wrow = We + ((size_t)l*HC + hc)*ED;
    const float* erow = etab + a*ED;
    float s = 0.f;
    #pragma unroll
    for (int k=0;k<ED;k++) s += erow[k]*wrow[k];
    ep[i] = s;
  }
  int tot = NL*512*HID;
  for (int j = i; j < tot; j += gridDim.x*blockDim.x){
    int l = j / (512*HID);
    int c = (j / HID) % 512;
    int k = j % HID;
    float v = (c < HC) ? Wl[((size_t)l*HC + c)*HID + k]
                       : Wr[((size_t)l*HC + (c-HC))*HID + k];
    Wlr[j] = f2b(v);
  }
}

// ---------------- CSR build ----------------
__global__ void deg_kernel(const int* __restrict__ dst, int* __restrict__ deg){
  int e = blockIdx.x*blockDim.x + threadIdx.x;
  if (e < NE) atomicAdd(&deg[dst[e]], 1);
}

__global__ void scanA_kernel(const int* __restrict__ deg, int* __restrict__ bsum){
  int t = threadIdx.x;
  int i = blockIdx.x*SCAN_B + t;
  int v = (i < NN) ? deg[i] : 0;
  #pragma unroll
  for (int o=1;o<64;o<<=1) v += __shfl_xor(v,o);
  __shared__ int ws[4];
  if ((t&63)==0) ws[t>>6] = v;
  __syncthreads();
  if (t==0) bsum[blockIdx.x] = ws[0]+ws[1]+ws[2]+ws[3];
}

__global__ void scanB_kernel(int* __restrict__ bsum){
  __shared__ int sh[256];
  int t = threadIdx.x;
  int v = (t < SCAN_NB) ? bsum[t] : 0;
  sh[t] = v;
  __syncthreads();
  for (int o=1;o<256;o<<=1){
    int u = (t>=o)?sh[t-o]:0;
    __syncthreads();
    sh[t]+=u;
    __syncthreads();
  }
  int excl = (t==0)?0:sh[t-1];
  if (t < SCAN_NB) bsum[t] = excl;
}

__global__ void scanC_kernel(const int* __restrict__ deg, const int* __restrict__ bsum,
                             int* __restrict__ rowp){
  int t = threadIdx.x, b = blockIdx.x;
  int i = b*SCAN_B + t;
  int v = (i<NN)?deg[i]:0;
  __shared__ int sh[256];
  sh[t]=v;
  __syncthreads();
  for (int o=1;o<256;o<<=1){
    int u=(t>=o)?sh[t-o]:0;
    __syncthreads();
    sh[t]+=u;
    __syncthreads();
  }
  if (i < NN) rowp[i] = bsum[b] + sh[t] - v;
  if (i == 0) rowp[NN] = NE;
}

__global__ void scatter_kernel(const int* __restrict__ src, const int* __restrict__ dst,
                               const int* __restrict__ attr, const int* __restrict__ rowp,
                               int* __restrict__ deg, int* __restrict__ csrp){
  int e = blockIdx.x*blockDim.x + threadIdx.x;
  if (e >= NE) return;
  int d = dst[e];
  int pos = rowp[d] + atomicSub(&deg[d], 1) - 1;
  csrp[pos] = src[e] | (attr[e] << 16);
}

// ---------------- degree-sorted order, DESCENDING, block-aggregated ----------------
__global__ void histE_kernel(const int* __restrict__ rowp, int* __restrict__ gbin,
                             int* __restrict__ bbase){
  __shared__ int lh[NBIN];
  int t = threadIdx.x, b = blockIdx.x;
  if (t < NBIN) lh[t] = 0;
  __syncthreads();
  int i = b*SCAN_B + t;
  if (i < NN){
    int dg = rowp[i+1] - rowp[i];
    if (dg > 63) dg = 63;
    atomicAdd(&lh[63 - dg], 1);
  }
  __syncthreads();
  if (t < NBIN){
    int c = lh[t];
    bbase[b*NBIN + t] = c ? atomicAdd(&gbin[t*BINPAD], c) : 0;
  }
}
__global__ void scanE_kernel(int* __restrict__ gbin){
  int t = threadIdx.x;
  int v = gbin[t*BINPAD];
  int s = v;
  #pragma unroll
  for (int o=1;o<64;o<<=1){
    int u = __shfl_up(s, o);
    if (t >= o) s += u;
  }
  gbin[t*BINPAD] = s - v;
}
__global__ void scatterE_kernel(const int* __restrict__ rowp, const int* __restrict__ gbin,
                                const int* __restrict__ bbase, int* __restrict__ order){
  __shared__ int lc[NBIN];
  int t = threadIdx.x, b = blockIdx.x;
  if (t < NBIN) lc[t] = 0;
  __syncthreads();
  int i = b*SCAN_B + t;
  if (i < NN){
    int dg = rowp[i+1] - rowp[i];
    if (dg > 63) dg = 63;
    int bin = 63 - dg;
    int r = atomicAdd(&lc[bin], 1);
    order[gbin[bin*BINPAD] + bbase[b*NBIN + bin] + r] = i;
  }
}

// ---------------- input GEMM: h = x @ inW.T + b ----------------
__global__ __launch_bounds__(256) void gemm_in_kernel(
    const float* __restrict__ X, const unsigned short* __restrict__ Wbf,
    const float* __restrict__ bias, float* __restrict__ hout, unsigned short* __restrict__ hbf)
{
  int wid = threadIdx.x >> 6, lane = threadIdx.x & 63;
  int row0 = blockIdx.x*128 + wid*32;
  int lr = lane & 15, lk = lane >> 4;
  short8 a[2][4];
  #pragma unroll
  for (int rt=0; rt<2; rt++){
    int r = row0 + rt*16 + lr; if (r >= NN) r = NN-1;
    const float* rp = X + (size_t)r*INDIM;
    #pragma unroll
    for (int ks=0; ks<4; ks++){
      const float* p = rp + ks*32 + lk*8;
      float4 u = ld4(p), v = ld4(p+4);
      short8 t;
      t[0]=(short)f2b(u.x); t[1]=(short)f2b(u.y); t[2]=(short)f2b(u.z); t[3]=(short)f2b(u.w);
      t[4]=(short)f2b(v.x); t[5]=(short)f2b(v.y); t[6]=(short)f2b(v.z); t[7]=(short)f2b(v.w);
      a[rt][ks] = t;
    }
  }
  f32x4 acc[2][4] = {};
  #pragma unroll
  for (int ct=0; ct<4; ct++){
    int c = ct*16 + lr;
    #pragma unroll
    for (int ks=0; ks<4; ks++){
      short8 b = *(const short8*)&Wbf[(size_t)c*INDIM + ks*32 + lk*8];
      #pragma unroll
      for (int rt=0; rt<2; rt++)
        acc[rt][ct] = __builtin_amdgcn_mfma_f32_16x16x32_bf16(a[rt][ks], b, acc[rt][ct], 0,0,0);
    }
  }
  #pragma unroll
  for (int rt=0; rt<2; rt++)
    #pragma unroll
    for (int ct=0; ct<4; ct++){
      int c = ct*16 + lr;
      float bv = bias[c];
      #pragma unroll
      for (int q=0;q<4;q++){
        int r = row0 + rt*16 + lk*4 + q;
        if (r < NN){
          float v = acc[rt][ct][q] + bv;
          hout[(size_t)r*HID + c] = v;
          hbf[(size_t)r*HID + c] = f2b(v);
        }
      }
    }
}

// ---------------- layer GEMM: xlr = h_bf @ Wlr.T + blr ([NN][512] fp16) ----------------
__global__ __launch_bounds__(256) void gemm_lr_kernel(
    const unsigned short* __restrict__ Abf, const unsigned short* __restrict__ Wbf,
    const float* __restrict__ bias, unsigned short* __restrict__ out)
{
  int wid = threadIdx.x >> 6, lane = threadIdx.x & 63;
  int row0 = blockIdx.x*128 + wid*32;
  int col0 = blockIdx.y*64;
  int lr = lane & 15, lk = lane >> 4;
  short8 a[2][2];
  #pragma unroll
  for (int rt=0; rt<2; rt++){
    int r = row0 + rt*16 + lr; if (r >= NN) r = NN-1;
    #pragma unroll
    for (int ks=0; ks<2; ks++)
      a[rt][ks] = *(const short8*)&Abf[(size_t)r*HID + ks*32 + lk*8];
  }
  f32x4 acc[2][4] = {};
  #pragma unroll
  for (int ct=0; ct<4; ct++){
    int c = col0 + ct*16 + lr;
    #pragma unroll
    for (int ks=0; ks<2; ks++){
      short8 b = *(const short8*)&Wbf[(size_t)c*HID + ks*32 + lk*8];
      #pragma unroll
      for (int rt=0; rt<2; rt++)
        acc[rt][ct] = __builtin_amdgcn_mfma_f32_16x16x32_bf16(a[rt][ks], b, acc[rt][ct], 0,0,0);
    }
  }
  #pragma unroll
  for (int rt=0; rt<2; rt++)
    #pragma unroll
    for (int ct=0; ct<4; ct++){
      int c = col0 + ct*16 + lr;
      float bv = bias[c];
      #pragma unroll
      for (int q=0;q<4;q++){
        int r = row0 + rt*16 + lk*4 + q;
        if (r < NN) out[(size_t)r*512 + c] = f2h(acc[rt][ct][q] + bv);
      }
    }
}

// ---------------- fused GATv2 aggregation + head-mean + LN + residual + relu ----------------
// round-12: TWO edges per wave. lane = (el = lane>>5 edge slot) x (q = lane&31).
// lane q covers channels q*8..q*8+7 (head q>>3, 8 lanes/head). 16B gather per lane,
// half-wave = 512B contiguous row. Logit reduce = 3 DPP steps over the 8-lane head group.
#define PBODY(P, U, WM)                                                        \
  {                                                                            \
    int a_ = (P) >> 16;                                                        \
    h2 x0 = bch((U).x), x1 = bch((U).y), x2 = bch((U).z), x3 = bch((U).w);     \
    h2 r0 = a_==0 ? xreA0 : (a_==1 ? xreB0 : xreC0);                           \
    h2 r1 = a_==0 ? xreA1 : (a_==1 ? xreB1 : xreC1);                           \
    h2 r2 = a_==0 ? xreA2 : (a_==1 ? xreB2 : xreC2);                           \
    h2 r3 = a_==0 ? xreA3 : (a_==1 ? xreB3 : xreC3);                           \
    h2 m0 = x0+r0, m1 = x1+r1, m2 = x2+r2, m3 = x3+r3;                         \
    h2 n0 = hab(m0), n1 = hab(m1), n2 = hab(m2), n3 = hab(m3);                 \
    float part = __builtin_amdgcn_fdot2(m0, av6_0, 0.f, false);                \
    part = __builtin_amdgcn_fdot2(m1, av6_1, part, false);                     \
    part = __builtin_amdgcn_fdot2(m2, av6_2, part, false);                     \
    part = __builtin_amdgcn_fdot2(m3, av6_3, part, false);                     \
    part = __builtin_amdgcn_fdot2(n0, av4_0, part, false);                     \
    part = __builtin_amdgcn_fdot2(n1, av4_1, part, false);                     \
    part = __builtin_amdgcn_fdot2(n2, av4_2, part, false);                     \
    part = __builtin_amdgcn_fdot2(n3, av4_3, part, false);                     \
    part = DPP_ADD(part, 0xB1);                                                \
    part = DPP_ADD(part, 0x4E);                                                \
    part = DPP_ADD(part, 0x141);                                               \
    float p_ = exp2f(part) * (WM);                                             \
    den += p_;                                                                 \
    a0f = fmaf(p_, (float)x0.x, a0f); a1f = fmaf(p_, (float)x0.y, a1f);        \
    a2f = fmaf(p_, (float)x1.x, a2f); a3f = fmaf(p_, (float)x1.y, a3f);        \
    a4f = fmaf(p_, (float)x2.x, a4f); a5f = fmaf(p_, (float)x2.y, a5f);        \
    a6f = fmaf(p_, (float)x3.x, a6f); a7f = fmaf(p_, (float)x3.y, a7f);        \
  }

#define GATHER(P) (*(const uint4*)(xlr + (((size_t)((P) & 0xFFFF)) << 9) + c8))

__global__ __launch_bounds__(256) void agg_kernel(
    const unsigned short* __restrict__ xlr,
    const int* __restrict__ rowp, const int* __restrict__ csrp,
    const int* __restrict__ order,
    const float* __restrict__ ep_l, const float* __restrict__ att_l,
    const float* __restrict__ bias_l, const float* __restrict__ g_l, const float* __restrict__ b_l,
    const float* __restrict__ h_in, float* __restrict__ h_out, unsigned short* __restrict__ hbf,
    int use_res, int do_relu)
{
  int idx = (blockIdx.x << 2) | (threadIdx.x >> 6);
  int lane = threadIdx.x & 63;
  if (idx >= NN) return;
  int d = order[idx];
  int el = lane >> 5;          // edge slot 0/1
  int q  = lane & 31;          // channel block; channels q*8..q*8+7
  int c8 = q << 3;

  // xr: 8 channels fp16 (replicated across halves)
  uint4 xru = *(const uint4*)(xlr + ((size_t)d << 9) + 256 + c8);
  h2 xr0 = bch(xru.x), xr1 = bch(xru.y), xr2 = bch(xru.z), xr3 = bch(xru.w);
  float xf0=(float)xr0.x, xf1=(float)xr0.y, xf2=(float)xr1.x, xf3=(float)xr1.y;
  float xf4=(float)xr2.x, xf5=(float)xr2.y, xf6=(float)xr3.x, xf7=(float)xr3.y;

  float4 eA0 = ld4(ep_l + c8),        eA1 = ld4(ep_l + c8 + 4);
  float4 eB0 = ld4(ep_l + HC + c8),   eB1 = ld4(ep_l + HC + c8 + 4);
  float4 eC0 = ld4(ep_l + 2*HC + c8), eC1 = ld4(ep_l + 2*HC + c8 + 4);
  h2 xreA0 = {(_Float16)(xf0+eA0.x), (_Float16)(xf1+eA0.y)};
  h2 xreA1 = {(_Float16)(xf2+eA0.z), (_Float16)(xf3+eA0.w)};
  h2 xreA2 = {(_Float16)(xf4+eA1.x), (_Float16)(xf5+eA1.y)};
  h2 xreA3 = {(_Float16)(xf6+eA1.z), (_Float16)(xf7+eA1.w)};
  h2 xreB0 = {(_Float16)(xf0+eB0.x), (_Float16)(xf1+eB0.y)};
  h2 xreB1 = {(_Float16)(xf2+eB0.z), (_Float16)(xf3+eB0.w)};
  h2 xreB2 = {(_Float16)(xf4+eB1.x), (_Float16)(xf5+eB1.y)};
  h2 xreB3 = {(_Float16)(xf6+eB1.z), (_Float16)(xf7+eB1.w)};
  h2 xreC0 = {(_Float16)(xf0+eC0.x), (_Float16)(xf1+eC0.y)};
  h2 xreC1 = {(_Float16)(xf2+eC0.z), (_Float16)(xf3+eC0.w)};
  h2 xreC2 = {(_Float16)(xf4+eC1.x), (_Float16)(xf5+eC1.y)};
  h2 xreC3 = {(_Float16)(xf6+eC1.z), (_Float16)(xf7+eC1.w)};

  float4 av0 = ld4(att_l + c8), av1 = ld4(att_l + c8 + 4);
  const float K6 = 0.6f*1.44269504f, K4 = 0.4f*1.44269504f;
  h2 av6_0 = {(_Float16)(av0.x*K6), (_Float16)(av0.y*K6)};
  h2 av6_1 = {(_Float16)(av0.z*K6), (_Float16)(av0.w*K6)};
  h2 av6_2 = {(_Float16)(av1.x*K6), (_Float16)(av1.y*K6)};
  h2 av6_3 = {(_Float16)(av1.z*K6), (_Float16)(av1.w*K6)};
  h2 av4_0 = {(_Float16)(av0.x*K4), (_Float16)(av0.y*K4)};
  h2 av4_1 = {(_Float16)(av0.z*K4), (_Float16)(av0.w*K4)};
  h2 av4_2 = {(_Float16)(av1.x*K4), (_Float16)(av1.y*K4)};
  h2 av4_3 = {(_Float16)(av1.z*K4), (_Float16)(av1.w*K4)};

  float den = 0.f;
  float a0f=0.f,a1f=0.f,a2f=0.f,a3f=0.f,a4f=0.f,a5f=0.f,a6f=0.f,a7f=0.f;

  int beg = rowp[d], stop = rowp[d+1];
  int i = beg;
  for (; i + 4 <= stop; i += 4){
    int pA = csrp[i + el];
    int pB = csrp[i + 2 + el];
    uint4 uA = GATHER(pA);
    uint4 uB = GATHER(pB);
    PBODY(pA, uA, 1.0f);
    PBODY(pB, uB, 1.0f);
  }
  if (i + 2 <= stop){
    int pA = csrp[i + el];
    uint4 uA = GATHER(pA);
    PBODY(pA, uA, 1.0f);
    i += 2;
  }
  if (i < stop){
    int pA = csrp[i];                   // both halves read same edge; el=1 masked
    uint4 uA = GATHER(pA);
    float wm = (el == 0) ? 1.0f : 0.0f;
    PBODY(pA, uA, wm);
  }

  // combine edge slots (xor 32)
  den += __shfl_xor(den, 32);
  a0f += __shfl_xor(a0f, 32); a1f += __shfl_xor(a1f, 32);
  a2f += __shfl_xor(a2f, 32); a3f += __shfl_xor(a3f, 32);
  a4f += __shfl_xor(a4f, 32); a5f += __shfl_xor(a5f, 32);
  a6f += __shfl_xor(a6f, 32); a7f += __shfl_xor(a7f, 32);

  float inv = (den > 0.f) ? 0.25f/den : 0.f;   // fold head-mean /4
  a0f*=inv; a1f*=inv; a2f*=inv; a3f*=inv; a4f*=inv; a5f*=inv; a6f*=inv; a7f*=inv;

  // head mean: pair heads within 16-row (ror8), then across rows (xor16)
  a0f = DPP_ADD(a0f, 0x128); a0f += __shfl_xor(a0f, 16);
  a1f = DPP_ADD(a1f, 0x128); a1f += __shfl_xor(a1f, 16);
  a2f = DPP_ADD(a2f, 0x128); a2f += __shfl_xor(a2f, 16);
  a3f = DPP_ADD(a3f, 0x128); a3f += __shfl_xor(a3f, 16);
  a4f = DPP_ADD(a4f, 0x128); a4f += __shfl_xor(a4f, 16);
  a5f = DPP_ADD(a5f, 0x128); a5f += __shfl_xor(a5f, 16);
  a6f = DPP_ADD(a6f, 0x128); a6f += __shfl_xor(a6f, 16);
  a7f = DPP_ADD(a7f, 0x128); a7f += __shfl_xor(a7f, 16);

  // lanes 0-7 now hold out channels (q&7)*8 .. +8
  int cc = (q & 7) << 3;
  float4 bv0 = ld4(bias_l + cc), bv1 = ld4(bias_l + cc + 4);
  float h0 = a0f + bv0.x, h1 = a1f + bv0.y, h2v = a2f + bv0.z, h3 = a3f + bv0.w;
  float h4 = a4f + bv1.x, h5 = a5f + bv1.y, h6 = a6f + bv1.z, h7 = a7f + bv1.w;

  float s1 = h0+h1+h2v+h3+h4+h5+h6+h7;
  float s2 = h0*h0+h1*h1+h2v*h2v+h3*h3+h4*h4+h5*h5+h6*h6+h7*h7;
  s1 = DPP_ADD(s1, 0xB1); s1 = DPP_ADD(s1, 0x4E); s1 = DPP_ADD(s1, 0x141);
  s2 = DPP_ADD(s2, 0xB1); s2 = DPP_ADD(s2, 0x4E); s2 = DPP_ADD(s2, 0x141);
  float mu  = s1 * (1.f/64.f);
  float var = fmaxf(s2*(1.f/64.f) - mu*mu, 0.f);
  float rstd = rsqrtf(var + 1e-5f);
  float4 gv0 = ld4(g_l + cc), gv1 = ld4(g_l + cc + 4);
  float4 bb0 = ld4(b_l + cc), bb1 = ld4(b_l + cc + 4);
  float r0 = (h0-mu)*rstd*gv0.x + bb0.x;
  float r1 = (h1-mu)*rstd*gv0.y + bb0.y;
  float r2 = (h2v-mu)*rstd*gv0.z + bb0.z;
  float r3 = (h3-mu)*rstd*gv0.w + bb0.w;
  float r4 = (h4-mu)*rstd*gv1.x + bb1.x;
  float r5 = (h5-mu)*rstd*gv1.y + bb1.y;
  float r6 = (h6-mu)*rstd*gv1.z + bb1.z;
  float r7 = (h7-mu)*rstd*gv1.w + bb1.w;
  if (use_res){
    float4 hv0 = ld4(h_in + (size_t)d*HID + cc);
    float4 hv1 = ld4(h_in + (size_t)d*HID + cc + 4);
    r0 += hv0.x; r1 += hv0.y; r2 += hv0.z; r3 += hv0.w;
    r4 += hv1.x; r5 += hv1.y; r6 += hv1.z; r7 += hv1.w;
  }
  if (do_relu){
    r0 = fmaxf(r0,0.f); r1 = fmaxf(r1,0.f); r2 = fmaxf(r2,0.f); r3 = fmaxf(r3,0.f);
    r4 = fmaxf(r4,0.f); r5 = fmaxf(r5,0.f); r6 = fmaxf(r6,0.f); r7 = fmaxf(r7,0.f);
  }
  if (lane < 8){
    float4 o0 = {r0, r1, r2, r3};
    float4 o1 = {r4, r5, r6, r7};
    *(float4*)(h_out + (size_t)d*HID + cc) = o0;
    *(float4*)(h_out + (size_t)d*HID + cc + 4) = o1;
    ushort4 ob0 = {f2b(r0), f2b(r1), f2b(r2), f2b(r3)};
    ushort4 ob1 = {f2b(r4), f2b(r5), f2b(r6), f2b(r7)};
    *(ushort4*)(hbf + (size_t)d*HID + cc) = ob0;
    *(ushort4*)(hbf + (size_t)d*HID + cc + 4) = ob1;
  }
}

// ---------------- launch ----------------
extern "C" void kernel_launch(void* const* d_in, const int* in_sizes, int n_in,
                              void* d_out, int out_size, void* d_ws, size_t ws_size,
                              hipStream_t stream){
  const float* x    = (const float*)d_in[0];
  const int*   ei   = (const int*)d_in[1];
  const int*   ea   = (const int*)d_in[2];
  const float* inW  = (const float*)d_in[3];
  const float* inb  = (const float*)d_in[4];
  const float* etab = (const float*)d_in[5];
  const float* Wl   = (const float*)d_in[6];
  const float* bl   = (const float*)d_in[7];
  const float* Wr   = (const float*)d_in[8];
  const float* br   = (const float*)d_in[9];
  const float* We   = (const float*)d_in[10];
  const float* att  = (const float*)d_in[11];
  const float* ob   = (const float*)d_in[12];
  const float* lg   = (const float*)d_in[13];
  const float* lb   = (const float*)d_in[14];

  char* w = (char*)d_ws;
  size_t off = 0;
  auto alloc = [&](size_t bytes)->char*{
    char* p = w + off;
    off = (off + bytes + 255) & ~(size_t)255;
    return p;
  };
  float* hA    = (float*)alloc((size_t)NN*HID*4);
  float* hB    = (float*)alloc((size_t)NN*HID*4);
  unsigned short* hbf = (unsigned short*)alloc((size_t)NN*HID*2);
  unsigned short* xlr = (unsigned short*)alloc((size_t)NN*512*2);
  unsigned short* inW_bf = (unsigned short*)alloc((size_t)HID*INDIM*2);
  unsigned short* Wlr    = (unsigned short*)alloc((size_t)NL*512*HID*2);
  float* blr   = (float*)alloc((size_t)NL*512*4);
  float* ep    = (float*)alloc((size_t)NL*3*HC*4);
  int*   deg   = (int*)alloc((size_t)NN*4);
  int*   bsum  = (int*)alloc((size_t)SCAN_NB*4);
  int*   rowp  = (int*)alloc((size_t)(NN+1)*4);
  int*   csrp  = (int*)alloc((size_t)NE*4);
  int*   gbin  = (int*)alloc((size_t)NBIN*BINPAD*4);
  int*   bbase = (int*)alloc((size_t)SCAN_NB*NBIN*4);
  int*   order = (int*)alloc((size_t)NN*4);

  hipMemsetAsync(deg, 0, (size_t)NN*4, stream);
  hipMemsetAsync(gbin, 0, (size_t)NBIN*BINPAD*4, stream);

  const int* srcp = ei;
  const int* dstp = ei + NE;
  deg_kernel<<<dim3((NE+255)/256), dim3(256), 0, stream>>>(dstp, deg);
  scanA_kernel<<<dim3(SCAN_NB), dim3(256), 0, stream>>>(deg, bsum);
  scanB_kernel<<<dim3(1), dim3(256), 0, stream>>>(bsum);
  scanC_kernel<<<dim3(SCAN_NB), dim3(256), 0, stream>>>(deg, bsum, rowp);
  scatter_kernel<<<dim3((NE+255)/256), dim3(256), 0, stream>>>(srcp, dstp, ea, rowp, deg, csrp);
  histE_kernel<<<dim3(SCAN_NB), dim3(256), 0, stream>>>(rowp, gbin, bbase);
  scanE_kernel<<<dim3(1), dim3(64), 0, stream>>>(gbin);
  scatterE_kernel<<<dim3(SCAN_NB), dim3(256), 0, stream>>>(rowp, gbin, bbase, order);
  prep_kernel<<<dim3(64), dim3(256), 0, stream>>>(inW, Wl, Wr, bl, br, etab, We, inW_bf, Wlr, blr, ep);

  const int MB = (NN + 127)/128;   // 391
  gemm_in_kernel<<<dim3(MB), dim3(256), 0, stream>>>(x, inW_bf, inb, hA, hbf);

  float* hcur = hA; float* hnext = hB;
  for (int l=0; l<NL; l++){
    gemm_lr_kernel<<<dim3(MB,8), dim3(256), 0, stream>>>(
        hbf, Wlr + (size_t)l*512*HID, blr + (size_t)l*512, xlr);
    float* hout = (l == NL-1) ? (float*)d_out : hnext;
    agg_kernel<<<dim3((NN+3)/4), dim3(256), 0, stream>>>(
        xlr, rowp, csrp, order,
        ep + (size_t)l*3*HC, att + (size_t)l*HC,
        ob + (size_t)l*HID, lg + (size_t)l*HID, lb + (size_t)l*HID,
        hcur, hout, hbf, (l >= NL/2) ? 1 : 0, (l < NL-1) ? 1 : 0);
    float* t = hcur; hcur = hnext; hnext = t;
  }
}

// Round 13
// 541.964 us; speedup vs baseline: 1.0543x; 1.0543x over previous
//
#include <hip/hip_runtime.h>
#include <hip/hip_bf16.h>
#include <hip/hip_fp16.h>
#include <math.h>

#define NN 50000
#define NE 400000
#define INDIM 128
#define HID 64
#define HC 256
#define NL 6
#define ED 16
#define SCAN_B 256
#define SCAN_NB ((NN + SCAN_B - 1)/SCAN_B)   // 196
#define NBIN 64
#define BINPAD 16

typedef __attribute__((ext_vector_type(8))) short short8;
typedef __attribute__((ext_vector_type(4))) float f32x4;
typedef _Float16 h2 __attribute__((ext_vector_type(2)));

static __device__ __forceinline__ float4 ld4(const float* p){ return *(const float4*)p; }
static __device__ __forceinline__ unsigned short f2b(float x){
  __hip_bfloat16 h = __float2bfloat16(x);
  return *(unsigned short*)&h;
}
static __device__ __forceinline__ unsigned short f2h(float x){
  __half h = __float2half(x);
  return *(unsigned short*)&h;
}
static __device__ __forceinline__ float b2f(unsigned short u){
  return __builtin_bit_cast(float, (unsigned)u << 16);
}

// DPP lane combine (pure VALU): 0xB1=xor1, 0x4E=xor2, 0x124=row_ror:4, 0x128=row_ror:8
#define DPP_ADD(X, CTRL) \
  ((X) + __builtin_bit_cast(float, __builtin_amdgcn_update_dpp(0, __builtin_bit_cast(int, (X)), (CTRL), 0xF, 0xF, true)))

// ---------------- prep: bf16 weights + Wl/Wr fusion + ep_table ----------------
__global__ void prep_kernel(const float* __restrict__ inW, const float* __restrict__ Wl,
                            const float* __restrict__ Wr, const float* __restrict__ bl,
                            const float* __restrict__ br, const float* __restrict__ etab,
                            const float* __restrict__ We,
                            unsigned short* __restrict__ inW_bf,
                            unsigned short* __restrict__ Wlr,
                            float* __restrict__ blr, float* __restrict__ ep){
  int i = blockIdx.x*blockDim.x + threadIdx.x;
  if (i < HID*INDIM) inW_bf[i] = f2b(inW[i]);
  if (i < NL*512){
    int l = i / 512, c = i % 512;
    blr[i] = (c < HC) ? bl[l*HC + c] : br[l*HC + (c-HC)];
  }
  if (i < NL*3*HC){
    int l  = i / (3*HC);
    int a  = (i / HC) % 3;
    int hc = i % HC;
    const float* wrow = We + ((size_t)l*HC + hc)*ED;
    const float* erow = etab + a*ED;
    float s = 0.f;
    #pragma unroll
    for (int k=0;k<ED;k++) s += erow[k]*wrow[k];
    ep[i] = s;
  }
  int tot = NL*512*HID;
  for (int j = i; j < tot; j += gridDim.x*blockDim.x){
    int l = j / (512*HID);
    int c = (j / HID) % 512;
    int k = j % HID;
    float v = (c < HC) ? Wl[((size_t)l*HC + c)*HID + k]
                       : Wr[((size_t)l*HC + (c-HC))*HID + k];
    Wlr[j] = f2b(v);
  }
}

// ---------------- CSR build ----------------
__global__ void deg_kernel(const int* __restrict__ dst, int* __restrict__ deg){
  int e = blockIdx.x*blockDim.x + threadIdx.x;
  if (e < NE) atomicAdd(&deg[dst[e]], 1);
}

__global__ void scanA_kernel(const int* __restrict__ deg, int* __restrict__ bsum){
  int t = threadIdx.x;
  int i = blockIdx.x*SCAN_B + t;
  int v = (i < NN) ? deg[i] : 0;
  #pragma unroll
  for (int o=1;o<64;o<<=1) v += __shfl_xor(v,o);
  __shared__ int ws[4];
  if ((t&63)==0) ws[t>>6] = v;
  __syncthreads();
  if (t==0) bsum[blockIdx.x] = ws[0]+ws[1]+ws[2]+ws[3];
}

__global__ void scanB_kernel(int* __restrict__ bsum){
  __shared__ int sh[256];
  int t = threadIdx.x;
  int v = (t < SCAN_NB) ? bsum[t] : 0;
  sh[t] = v;
  __syncthreads();
  for (int o=1;o<256;o<<=1){
    int u = (t>=o)?sh[t-o]:0;
    __syncthreads();
    sh[t]+=u;
    __syncthreads();
  }
  int excl = (t==0)?0:sh[t-1];
  if (t < SCAN_NB) bsum[t] = excl;
}

__global__ void scanC_kernel(const int* __restrict__ deg, const int* __restrict__ bsum,
                             int* __restrict__ rowp){
  int t = threadIdx.x, b = blockIdx.x;
  int i = b*SCAN_B + t;
  int v = (i<NN)?deg[i]:0;
  __shared__ int sh[256];
  sh[t]=v;
  __syncthreads();
  for (int o=1;o<256;o<<=1){
    int u=(t>=o)?sh[t-o]:0;
    __syncthreads();
    sh[t]+=u;
    __syncthreads();
  }
  if (i < NN) rowp[i] = bsum[b] + sh[t] - v;
  if (i == 0) rowp[NN] = NE;
}

__global__ void scatter_kernel(const int* __restrict__ src, const int* __restrict__ dst,
                               const int* __restrict__ attr, const int* __restrict__ rowp,
                               int* __restrict__ deg, int* __restrict__ csrp){
  int e = blockIdx.x*blockDim.x + threadIdx.x;
  if (e >= NE) return;
  int d = dst[e];
  int pos = rowp[d] + atomicSub(&deg[d], 1) - 1;
  csrp[pos] = src[e] | (attr[e] << 16);
}

// ---------------- degree-sorted order, DESCENDING, block-aggregated ----------------
__global__ void histE_kernel(const int* __restrict__ rowp, int* __restrict__ gbin,
                             int* __restrict__ bbase){
  __shared__ int lh[NBIN];
  int t = threadIdx.x, b = blockIdx.x;
  if (t < NBIN) lh[t] = 0;
  __syncthreads();
  int i = b*SCAN_B + t;
  if (i < NN){
    int dg = rowp[i+1] - rowp[i];
    if (dg > 63) dg = 63;
    atomicAdd(&lh[63 - dg], 1);
  }
  __syncthreads();
  if (t < NBIN){
    int c = lh[t];
    bbase[b*NBIN + t] = c ? atomicAdd(&gbin[t*BINPAD], c) : 0;
  }
}
__global__ void scanE_kernel(int* __restrict__ gbin){
  int t = threadIdx.x;
  int v = gbin[t*BINPAD];
  int s = v;
  #pragma unroll
  for (int o=1;o<64;o<<=1){
    int u = __shfl_up(s, o);
    if (t >= o) s += u;
  }
  gbin[t*BINPAD] = s - v;
}
__global__ void scatterE_kernel(const int* __restrict__ rowp, const int* __restrict__ gbin,
                                const int* __restrict__ bbase, int* __restrict__ order){
  __shared__ int lc[NBIN];
  int t = threadIdx.x, b = blockIdx.x;
  if (t < NBIN) lc[t] = 0;
  __syncthreads();
  int i = b*SCAN_B + t;
  if (i < NN){
    int dg = rowp[i+1] - rowp[i];
    if (dg > 63) dg = 63;
    int bin = 63 - dg;
    int r = atomicAdd(&lc[bin], 1);
    order[gbin[bin*BINPAD] + bbase[b*NBIN + bin] + r] = i;
  }
}

// ---------------- input GEMM: hbf = bf16(x @ inW.T + b) ----------------
__global__ __launch_bounds__(256) void gemm_in_kernel(
    const float* __restrict__ X, const unsigned short* __restrict__ Wbf,
    const float* __restrict__ bias, unsigned short* __restrict__ hbf)
{
  int wid = threadIdx.x >> 6, lane = threadIdx.x & 63;
  int row0 = blockIdx.x*128 + wid*32;
  int lr = lane & 15, lk = lane >> 4;
  short8 a[2][4];
  #pragma unroll
  for (int rt=0; rt<2; rt++){
    int r = row0 + rt*16 + lr; if (r >= NN) r = NN-1;
    const float* rp = X + (size_t)r*INDIM;
    #pragma unroll
    for (int ks=0; ks<4; ks++){
      const float* p = rp + ks*32 + lk*8;
      float4 u = ld4(p), v = ld4(p+4);
      short8 t;
      t[0]=(short)f2b(u.x); t[1]=(short)f2b(u.y); t[2]=(short)f2b(u.z); t[3]=(short)f2b(u.w);
      t[4]=(short)f2b(v.x); t[5]=(short)f2b(v.y); t[6]=(short)f2b(v.z); t[7]=(short)f2b(v.w);
      a[rt][ks] = t;
    }
  }
  f32x4 acc[2][4] = {};
  #pragma unroll
  for (int ct=0; ct<4; ct++){
    int c = ct*16 + lr;
    #pragma unroll
    for (int ks=0; ks<4; ks++){
      short8 b = *(const short8*)&Wbf[(size_t)c*INDIM + ks*32 + lk*8];
      #pragma unroll
      for (int rt=0; rt<2; rt++)
        acc[rt][ct] = __builtin_amdgcn_mfma_f32_16x16x32_bf16(a[rt][ks], b, acc[rt][ct], 0,0,0);
    }
  }
  #pragma unroll
  for (int rt=0; rt<2; rt++)
    #pragma unroll
    for (int ct=0; ct<4; ct++){
      int c = ct*16 + lr;
      float bv = bias[c];
      #pragma unroll
      for (int q=0;q<4;q++){
        int r = row0 + rt*16 + lk*4 + q;
        if (r < NN) hbf[(size_t)r*HID + c] = f2b(acc[rt][ct][q] + bv);
      }
    }
}

// ---------------- layer GEMM: xlr = h_bf @ Wlr.T + blr ([NN][512] fp16) ----------------
__global__ __launch_bounds__(256) void gemm_lr_kernel(
    const unsigned short* __restrict__ Abf, const unsigned short* __restrict__ Wbf,
    const float* __restrict__ bias, unsigned short* __restrict__ out)
{
  int wid = threadIdx.x >> 6, lane = threadIdx.x & 63;
  int row0 = blockIdx.x*128 + wid*32;
  int col0 = blockIdx.y*64;
  int lr = lane & 15, lk = lane >> 4;
  short8 a[2][2];
  #pragma unroll
  for (int rt=0; rt<2; rt++){
    int r = row0 + rt*16 + lr; if (r >= NN) r = NN-1;
    #pragma unroll
    for (int ks=0; ks<2; ks++)
      a[rt][ks] = *(const short8*)&Abf[(size_t)r*HID + ks*32 + lk*8];
  }
  f32x4 acc[2][4] = {};
  #pragma unroll
  for (int ct=0; ct<4; ct++){
    int c = col0 + ct*16 + lr;
    #pragma unroll
    for (int ks=0; ks<2; ks++){
      short8 b = *(const short8*)&Wbf[(size_t)c*HID + ks*32 + lk*8];
      #pragma unroll
      for (int rt=0; rt<2; rt++)
        acc[rt][ct] = __builtin_amdgcn_mfma_f32_16x16x32_bf16(a[rt][ks], b, acc[rt][ct], 0,0,0);
    }
  }
  #pragma unroll
  for (int rt=0; rt<2; rt++)
    #pragma unroll
    for (int ct=0; ct<4; ct++){
      int c = col0 + ct*16 + lr;
      float bv = bias[c];
      #pragma unroll
      for (int q=0;q<4;q++){
        int r = row0 + rt*16 + lk*4 + q;
        if (r < NN) out[(size_t)r*512 + c] = f2h(acc[rt][ct][q] + bv);
      }
    }
}

// ---------------- fused GATv2 aggregation + head-mean + LN + residual + relu ----------------
// round-13: round-11 structure (4-wide, 4ch/lane, DPP); bf16-only intermediate h:
// residual reads hbf, output writes hbf (or fp32 d_out at last layer)
#define EDGE_BODY(UX, UY, A)                                                   \
  {                                                                            \
    h2 x2a = __builtin_bit_cast(h2, (UX));                                     \
    h2 x2b = __builtin_bit_cast(h2, (UY));                                     \
    h2 m2a = x2a + ((A)==0 ? xre0a : ((A)==1 ? xre1a : xre2a));                \
    h2 m2b = x2b + ((A)==0 ? xre0b : ((A)==1 ? xre1b : xre2b));                \
    h2 n2a = __builtin_bit_cast(h2, __builtin_bit_cast(unsigned, m2a) & 0x7FFF7FFFu); \
    h2 n2b = __builtin_bit_cast(h2, __builtin_bit_cast(unsigned, m2b) & 0x7FFF7FFFu); \
    float part = __builtin_amdgcn_fdot2(m2a, av6a, 0.f, false);                \
    part = __builtin_amdgcn_fdot2(m2b, av6b, part, false);                     \
    part = __builtin_amdgcn_fdot2(n2a, av4a, part, false);                     \
    part = __builtin_amdgcn_fdot2(n2b, av4b, part, false);                     \
    part = DPP_ADD(part, 0xB1);                                                \
    part = DPP_ADD(part, 0x4E);                                                \
    part = DPP_ADD(part, 0x124);                                               \
    part = DPP_ADD(part, 0x128);                                               \
    float p = exp2f(part);                                                     \
    den += p;                                                                  \
    ax = fmaf(p, (float)x2a.x, ax);                                            \
    ay = fmaf(p, (float)x2a.y, ay);                                            \
    az = fmaf(p, (float)x2b.x, az);                                            \
    aw = fmaf(p, (float)x2b.y, aw);                                            \
  }

__global__ __launch_bounds__(256) void agg_kernel(
    const unsigned short* __restrict__ xlr,
    const int* __restrict__ rowp, const int* __restrict__ csrp,
    const int* __restrict__ order,
    const float* __restrict__ ep_l, const float* __restrict__ att_l,
    const float* __restrict__ bias_l, const float* __restrict__ g_l, const float* __restrict__ b_l,
    unsigned short* __restrict__ hbf, float* __restrict__ out_last,
    int use_res, int do_relu, int last)
{
  int idx = (blockIdx.x << 2) | (threadIdx.x >> 6);
  int lane = threadIdx.x & 63;
  if (idx >= NN) return;
  int d = order[idx];
  int cb = lane << 2;

  uint2 xru = *(const uint2*)(xlr + ((size_t)d << 9) + 256 + cb);
  h2 xr2a = __builtin_bit_cast(h2, xru.x);
  h2 xr2b = __builtin_bit_cast(h2, xru.y);
  float xrf0 = (float)xr2a.x, xrf1 = (float)xr2a.y;
  float xrf2 = (float)xr2b.x, xrf3 = (float)xr2b.y;

  float4 ev0 = ld4(ep_l + cb);
  float4 ev1 = ld4(ep_l + HC + cb);
  float4 ev2 = ld4(ep_l + 2*HC + cb);
  h2 xre0a = {(_Float16)(xrf0+ev0.x), (_Float16)(xrf1+ev0.y)};
  h2 xre0b = {(_Float16)(xrf2+ev0.z), (_Float16)(xrf3+ev0.w)};
  h2 xre1a = {(_Float16)(xrf0+ev1.x), (_Float16)(xrf1+ev1.y)};
  h2 xre1b = {(_Float16)(xrf2+ev1.z), (_Float16)(xrf3+ev1.w)};
  h2 xre2a = {(_Float16)(xrf0+ev2.x), (_Float16)(xrf1+ev2.y)};
  h2 xre2b = {(_Float16)(xrf2+ev2.z), (_Float16)(xrf3+ev2.w)};

  float4 av = ld4(att_l + cb);
  const float K6 = 0.6f*1.44269504f, K4 = 0.4f*1.44269504f;
  h2 av6a = {(_Float16)(av.x*K6), (_Float16)(av.y*K6)};
  h2 av6b = {(_Float16)(av.z*K6), (_Float16)(av.w*K6)};
  h2 av4a = {(_Float16)(av.x*K4), (_Float16)(av.y*K4)};
  h2 av4b = {(_Float16)(av.z*K4), (_Float16)(av.w*K4)};

  float den = 0.f;
  float ax=0.f, ay=0.f, az=0.f, aw=0.f;

  int beg = rowp[d], stop = rowp[d+1];
  int i = beg;
  for (; i + 4 <= stop; i += 4){
    int p0 = csrp[i], p1 = csrp[i+1], p2 = csrp[i+2], p3 = csrp[i+3];
    uint2 u0 = *(const uint2*)(xlr + ((size_t)(p0 & 0xFFFF) << 9) + cb);
    uint2 u1 = *(const uint2*)(xlr + ((size_t)(p1 & 0xFFFF) << 9) + cb);
    uint2 u2 = *(const uint2*)(xlr + ((size_t)(p2 & 0xFFFF) << 9) + cb);
    uint2 u3 = *(const uint2*)(xlr + ((size_t)(p3 & 0xFFFF) << 9) + cb);
    int a0 = p0 >> 16, a1 = p1 >> 16, a2 = p2 >> 16, a3 = p3 >> 16;
    EDGE_BODY(u0.x, u0.y, a0);
    EDGE_BODY(u1.x, u1.y, a1);
    EDGE_BODY(u2.x, u2.y, a2);
    EDGE_BODY(u3.x, u3.y, a3);
  }
  if (i + 2 <= stop){
    int p0 = csrp[i], p1 = csrp[i+1];
    uint2 u0 = *(const uint2*)(xlr + ((size_t)(p0 & 0xFFFF) << 9) + cb);
    uint2 u1 = *(const uint2*)(xlr + ((size_t)(p1 & 0xFFFF) << 9) + cb);
    int a0 = p0 >> 16, a1 = p1 >> 16;
    EDGE_BODY(u0.x, u0.y, a0);
    EDGE_BODY(u1.x, u1.y, a1);
    i += 2;
  }
  if (i < stop){
    int p0 = csrp[i];
    uint2 u0 = *(const uint2*)(xlr + ((size_t)(p0 & 0xFFFF) << 9) + cb);
    int a0 = p0 >> 16;
    EDGE_BODY(u0.x, u0.y, a0);
  }

  float inv = (den > 0.f) ? 1.f/den : 0.f;
  ax *= inv; ay *= inv; az *= inv; aw *= inv;

  ax += __shfl_xor(ax,16); ay += __shfl_xor(ay,16); az += __shfl_xor(az,16); aw += __shfl_xor(aw,16);
  ax += __shfl_xor(ax,32); ay += __shfl_xor(ay,32); az += __shfl_xor(az,32); aw += __shfl_xor(aw,32);

  int cc = (lane & 15) << 2;
  float4 bv = ld4(bias_l + cc);
  float h0 = ax*0.25f + bv.x;
  float h1 = ay*0.25f + bv.y;
  float h2v = az*0.25f + bv.z;
  float h3 = aw*0.25f + bv.w;

  float s1 = h0+h1+h2v+h3;
  float s2 = h0*h0 + h1*h1 + h2v*h2v + h3*h3;
  s1 += __shfl_xor(s1,1); s2 += __shfl_xor(s2,1);
  s1 += __shfl_xor(s1,2); s2 += __shfl_xor(s2,2);
  s1 += __shfl_xor(s1,4); s2 += __shfl_xor(s2,4);
  s1 += __shfl_xor(s1,8); s2 += __shfl_xor(s2,8);
  float mu  = s1 * (1.f/64.f);
  float var = fmaxf(s2*(1.f/64.f) - mu*mu, 0.f);
  float rstd = rsqrtf(var + 1e-5f);
  float4 gv  = ld4(g_l + cc);
  float4 bbv = ld4(b_l + cc);
  float r0 = (h0-mu)*rstd*gv.x + bbv.x;
  float r1 = (h1-mu)*rstd*gv.y + bbv.y;
  float r2 = (h2v-mu)*rstd*gv.z + bbv.z;
  float r3 = (h3-mu)*rstd*gv.w + bbv.w;
  if (use_res){
    ushort4 hv = *(const ushort4*)(hbf + (size_t)d*HID + cc);
    r0 += b2f(hv.x); r1 += b2f(hv.y); r2 += b2f(hv.z); r3 += b2f(hv.w);
  }
  if (do_relu){
    r0 = fmaxf(r0, 0.f); r1 = fmaxf(r1, 0.f);
    r2 = fmaxf(r2, 0.f); r3 = fmaxf(r3, 0.f);
  }
  if (lane < 16){
    if (last){
      float4 o = {r0, r1, r2, r3};
      *(float4*)(out_last + (size_t)d*HID + cc) = o;
    } else {
      ushort4 obv = {f2b(r0), f2b(r1), f2b(r2), f2b(r3)};
      *(ushort4*)(hbf + (size_t)d*HID + cc) = obv;
    }
  }
}

// ---------------- launch ----------------
extern "C" void kernel_launch(void* const* d_in, const int* in_sizes, int n_in,
                              void* d_out, int out_size, void* d_ws, size_t ws_size,
                              hipStream_t stream){
  const float* x    = (const float*)d_in[0];
  const int*   ei   = (const int*)d_in[1];
  const int*   ea   = (const int*)d_in[2];
  const float* inW  = (const float*)d_in[3];
  const float* inb  = (const float*)d_in[4];
  const float* etab = (const float*)d_in[5];
  const float* Wl   = (const float*)d_in[6];
  const float* bl   = (const float*)d_in[7];
  const float* Wr   = (const float*)d_in[8];
  const float* br   = (const float*)d_in[9];
  const float* We   = (const float*)d_in[10];
  const float* att  = (const float*)d_in[11];
  const float* ob   = (const float*)d_in[12];
  const float* lg   = (const float*)d_in[13];
  const float* lb   = (const float*)d_in[14];

  char* w = (char*)d_ws;
  size_t off = 0;
  auto alloc = [&](size_t bytes)->char*{
    char* p = w + off;
    off = (off + bytes + 255) & ~(size_t)255;
    return p;
  };
  unsigned short* hbf = (unsigned short*)alloc((size_t)NN*HID*2);
  unsigned short* xlr = (unsigned short*)alloc((size_t)NN*512*2);
  unsigned short* inW_bf = (unsigned short*)alloc((size_t)HID*INDIM*2);
  unsigned short* Wlr    = (unsigned short*)alloc((size_t)NL*512*HID*2);
  float* blr   = (float*)alloc((size_t)NL*512*4);
  float* ep    = (float*)alloc((size_t)NL*3*HC*4);
  int*   deg   = (int*)alloc((size_t)NN*4);
  int*   bsum  = (int*)alloc((size_t)SCAN_NB*4);
  int*   rowp  = (int*)alloc((size_t)(NN+1)*4);
  int*   csrp  = (int*)alloc((size_t)NE*4);
  int*   gbin  = (int*)alloc((size_t)NBIN*BINPAD*4);
  int*   bbase = (int*)alloc((size_t)SCAN_NB*NBIN*4);
  int*   order = (int*)alloc((size_t)NN*4);

  hipMemsetAsync(deg, 0, (size_t)NN*4, stream);
  hipMemsetAsync(gbin, 0, (size_t)NBIN*BINPAD*4, stream);

  const int* srcp = ei;
  const int* dstp = ei + NE;
  deg_kernel<<<dim3((NE+255)/256), dim3(256), 0, stream>>>(dstp, deg);
  scanA_kernel<<<dim3(SCAN_NB), dim3(256), 0, stream>>>(deg, bsum);
  scanB_kernel<<<dim3(1), dim3(256), 0, stream>>>(bsum);
  scanC_kernel<<<dim3(SCAN_NB), dim3(256), 0, stream>>>(deg, bsum, rowp);
  scatter_kernel<<<dim3((NE+255)/256), dim3(256), 0, stream>>>(srcp, dstp, ea, rowp, deg, csrp);
  histE_kernel<<<dim3(SCAN_NB), dim3(256), 0, stream>>>(rowp, gbin, bbase);
  scanE_kernel<<<dim3(1), dim3(64), 0, stream>>>(gbin);
  scatterE_kernel<<<dim3(SCAN_NB), dim3(256), 0, stream>>>(rowp, gbin, bbase, order);
  prep_kernel<<<dim3(64), dim3(256), 0, stream>>>(inW, Wl, Wr, bl, br, etab, We, inW_bf, Wlr, blr, ep);

  const int MB = (NN + 127)/128;   // 391
  gemm_in_kernel<<<dim3(MB), dim3(256), 0, stream>>>(x, inW_bf, inb, hbf);

  for (int l=0; l<NL; l++){
    gemm_lr_kernel<<<dim3(MB,8), dim3(256), 0, stream>>>(
        hbf, Wlr + (size_t)l*512*HID, blr + (size_t)l*512, xlr);
    agg_kernel<<<dim3((NN+3)/4), dim3(256), 0, stream>>>(
        xlr, rowp, csrp, order,
        ep + (size_t)l*3*HC, att + (size_t)l*HC,
        ob + (size_t)l*HID, lg + (size_t)l*HID, lb + (size_t)l*HID,
        hbf, (float*)d_out,
        (l >= NL/2) ? 1 : 0, (l < NL-1) ? 1 : 0, (l == NL-1) ? 1 : 0);
  }
}

// Round 14
// 523.281 us; speedup vs baseline: 1.0919x; 1.0357x over previous
//
#include <hip/hip_runtime.h>
#include <hip/hip_bf16.h>
#include <hip/hip_fp16.h>
#include <math.h>

#define NN 50000
#define NE 400000
#define INDIM 128
#define HID 64
#define HC 256
#define NL 6
#define ED 16
#define SCAN_B 256
#define SCAN_NB ((NN + SCAN_B - 1)/SCAN_B)   // 196
#define NBIN 64
#define BINPAD 16

typedef __attribute__((ext_vector_type(8))) short short8;
typedef __attribute__((ext_vector_type(4))) float f32x4;
typedef _Float16 h2 __attribute__((ext_vector_type(2)));

static __device__ __forceinline__ float4 ld4(const float* p){ return *(const float4*)p; }
static __device__ __forceinline__ unsigned short f2b(float x){
  __hip_bfloat16 h = __float2bfloat16(x);
  return *(unsigned short*)&h;
}
static __device__ __forceinline__ unsigned short f2h(float x){
  __half h = __float2half(x);
  return *(unsigned short*)&h;
}
static __device__ __forceinline__ float b2f(unsigned short u){
  return __builtin_bit_cast(float, (unsigned)u << 16);
}

// DPP lane combine (pure VALU): 0xB1=xor1, 0x4E=xor2, 0x124=row_ror:4, 0x128=row_ror:8
#define DPP_ADD(X, CTRL) \
  ((X) + __builtin_bit_cast(float, __builtin_amdgcn_update_dpp(0, __builtin_bit_cast(int, (X)), (CTRL), 0xF, 0xF, true)))

// ---------------- prep: bf16 weights + Wl/Wr fusion + ep_table ----------------
__global__ void prep_kernel(const float* __restrict__ inW, const float* __restrict__ Wl,
                            const float* __restrict__ Wr, const float* __restrict__ bl,
                            const float* __restrict__ br, const float* __restrict__ etab,
                            const float* __restrict__ We,
                            unsigned short* __restrict__ inW_bf,
                            unsigned short* __restrict__ Wlr,
                            float* __restrict__ blr, float* __restrict__ ep){
  int i = blockIdx.x*blockDim.x + threadIdx.x;
  if (i < HID*INDIM) inW_bf[i] = f2b(inW[i]);
  if (i < NL*512){
    int l = i / 512, c = i % 512;
    blr[i] = (c < HC) ? bl[l*HC + c] : br[l*HC + (c-HC)];
  }
  if (i < NL*3*HC){
    int l  = i / (3*HC);
    int a  = (i / HC) % 3;
    int hc = i % HC;
    const float* wrow = We + ((size_t)l*HC + hc)*ED;
    const float* erow = etab + a*ED;
    float s = 0.f;
    #pragma unroll
    for (int k=0;k<ED;k++) s += erow[k]*wrow[k];
    ep[i] = s;
  }
  int tot = NL*512*HID;
  for (int j = i; j < tot; j += gridDim.x*blockDim.x){
    int l = j / (512*HID);
    int c = (j / HID) % 512;
    int k = j % HID;
    float v = (c < HC) ? Wl[((size_t)l*HC + c)*HID + k]
                       : Wr[((size_t)l*HC + (c-HC))*HID + k];
    Wlr[j] = f2b(v);
  }
}

// ---------------- CSR build + degree-sort (fused pre-pass) ----------------
__global__ void deg_kernel(const int* __restrict__ dst, int* __restrict__ deg,
                           int* __restrict__ gbin){
  int e = blockIdx.x*blockDim.x + threadIdx.x;
  if (e < NBIN*BINPAD) gbin[e] = 0;
  if (e < NE) atomicAdd(&deg[dst[e]], 1);
}

// block edge-count sums + per-block degree histogram (bin = 63-min(deg,63), descending)
__global__ void scanA_kernel(const int* __restrict__ deg, int* __restrict__ bsum,
                             int* __restrict__ gbin, int* __restrict__ bbase){
  __shared__ int lh[NBIN];
  __shared__ int ws[4];
  int t = threadIdx.x, b = blockIdx.x;
  if (t < NBIN) lh[t] = 0;
  __syncthreads();
  int i = b*SCAN_B + t;
  int v = (i < NN) ? deg[i] : 0;
  if (i < NN){
    int dg = v > 63 ? 63 : v;
    atomicAdd(&lh[63 - dg], 1);
  }
  int s = v;
  #pragma unroll
  for (int o=1;o<64;o<<=1) s += __shfl_xor(s,o);
  if ((t&63)==0) ws[t>>6] = s;
  __syncthreads();
  if (t==0) bsum[b] = ws[0]+ws[1]+ws[2]+ws[3];
  if (t < NBIN){
    int c = lh[t];
    bbase[b*NBIN + t] = c ? atomicAdd(&gbin[t*BINPAD], c) : 0;
  }
}

// scan of block sums + scan of 64 degree bins
__global__ void scanB_kernel(int* __restrict__ bsum, int* __restrict__ gbin){
  __shared__ int sh[256];
  int t = threadIdx.x;
  int v = (t < SCAN_NB) ? bsum[t] : 0;
  sh[t] = v;
  __syncthreads();
  for (int o=1;o<256;o<<=1){
    int u = (t>=o)?sh[t-o]:0;
    __syncthreads();
    sh[t]+=u;
    __syncthreads();
  }
  int excl = (t==0)?0:sh[t-1];
  if (t < SCAN_NB) bsum[t] = excl;
  if (t < NBIN){
    int v2 = gbin[t*BINPAD];
    int s2 = v2;
    #pragma unroll
    for (int o=1;o<64;o<<=1){
      int u = __shfl_up(s2, o);
      if (t >= o) s2 += u;
    }
    gbin[t*BINPAD] = s2 - v2;
  }
}

// rowp + degree-sorted order scatter
__global__ void scanC_kernel(const int* __restrict__ deg, const int* __restrict__ bsum,
                             const int* __restrict__ gbin, const int* __restrict__ bbase,
                             int* __restrict__ rowp, int* __restrict__ order){
  __shared__ int sh[256];
  __shared__ int lc[NBIN];
  int t = threadIdx.x, b = blockIdx.x;
  if (t < NBIN) lc[t] = 0;
  int i = b*SCAN_B + t;
  int v = (i<NN)?deg[i]:0;
  sh[t]=v;
  __syncthreads();
  for (int o=1;o<256;o<<=1){
    int u=(t>=o)?sh[t-o]:0;
    __syncthreads();
    sh[t]+=u;
    __syncthreads();
  }
  if (i < NN) rowp[i] = bsum[b] + sh[t] - v;
  if (i == 0) rowp[NN] = NE;
  if (i < NN){
    int dg = v > 63 ? 63 : v;
    int bin = 63 - dg;
    int r = atomicAdd(&lc[bin], 1);
    order[gbin[bin*BINPAD] + bbase[b*NBIN + bin] + r] = i;
  }
}

// scatter packed (src | attr<<16); consumes deg as a countdown counter
__global__ void scatter_kernel(const int* __restrict__ src, const int* __restrict__ dst,
                               const int* __restrict__ attr, const int* __restrict__ rowp,
                               int* __restrict__ deg, int* __restrict__ csrp){
  int e = blockIdx.x*blockDim.x + threadIdx.x;
  if (e >= NE) return;
  int d = dst[e];
  int pos = rowp[d] + atomicSub(&deg[d], 1) - 1;
  csrp[pos] = src[e] | (attr[e] << 16);
}

// ---------------- input GEMM: hbf = bf16(x @ inW.T + b) ----------------
// operand-swapped MFMA: lane holds 4 consecutive output channels -> packed 8B stores
__global__ __launch_bounds__(256) void gemm_in_kernel(
    const float* __restrict__ X, const unsigned short* __restrict__ Wbf,
    const float* __restrict__ bias, unsigned short* __restrict__ hbf)
{
  int wid = threadIdx.x >> 6, lane = threadIdx.x & 63;
  int row0 = blockIdx.x*128 + wid*32;
  int lr = lane & 15, lk = lane >> 4;
  short8 a[2][4];
  #pragma unroll
  for (int rt=0; rt<2; rt++){
    int r = row0 + rt*16 + lr; if (r >= NN) r = NN-1;
    const float* rp = X + (size_t)r*INDIM;
    #pragma unroll
    for (int ks=0; ks<4; ks++){
      const float* p = rp + ks*32 + lk*8;
      float4 u = ld4(p), v = ld4(p+4);
      short8 t;
      t[0]=(short)f2b(u.x); t[1]=(short)f2b(u.y); t[2]=(short)f2b(u.z); t[3]=(short)f2b(u.w);
      t[4]=(short)f2b(v.x); t[5]=(short)f2b(v.y); t[6]=(short)f2b(v.z); t[7]=(short)f2b(v.w);
      a[rt][ks] = t;
    }
  }
  f32x4 acc[2][4] = {};
  #pragma unroll
  for (int ct=0; ct<4; ct++){
    int c = ct*16 + lr;
    #pragma unroll
    for (int ks=0; ks<4; ks++){
      short8 b = *(const short8*)&Wbf[(size_t)c*INDIM + ks*32 + lk*8];
      #pragma unroll
      for (int rt=0; rt<2; rt++)
        acc[rt][ct] = __builtin_amdgcn_mfma_f32_16x16x32_bf16(b, a[rt][ks], acc[rt][ct], 0,0,0);
    }
  }
  // D[i=Wcol][j=hrow]: row = row0+rt*16+lr, cols = ct*16 + lk*4 + {0..3}
  #pragma unroll
  for (int rt=0; rt<2; rt++){
    int r = row0 + rt*16 + lr;
    if (r < NN){
      #pragma unroll
      for (int ct=0; ct<4; ct++){
        int cq = ct*16 + (lk<<2);
        float4 bv = ld4(bias + cq);
        ushort4 o = { f2b(acc[rt][ct][0]+bv.x), f2b(acc[rt][ct][1]+bv.y),
                      f2b(acc[rt][ct][2]+bv.z), f2b(acc[rt][ct][3]+bv.w) };
        *(ushort4*)&hbf[(size_t)r*HID + cq] = o;
      }
    }
  }
}

// ---------------- layer GEMM: xlr = h_bf @ Wlr.T + blr ([NN][512] fp16) ----------------
__global__ __launch_bounds__(256) void gemm_lr_kernel(
    const unsigned short* __restrict__ Abf, const unsigned short* __restrict__ Wbf,
    const float* __restrict__ bias, unsigned short* __restrict__ out)
{
  int wid = threadIdx.x >> 6, lane = threadIdx.x & 63;
  int row0 = blockIdx.x*128 + wid*32;
  int col0 = blockIdx.y*64;
  int lr = lane & 15, lk = lane >> 4;
  short8 a[2][2];
  #pragma unroll
  for (int rt=0; rt<2; rt++){
    int r = row0 + rt*16 + lr; if (r >= NN) r = NN-1;
    #pragma unroll
    for (int ks=0; ks<2; ks++)
      a[rt][ks] = *(const short8*)&Abf[(size_t)r*HID + ks*32 + lk*8];
  }
  f32x4 acc[2][4] = {};
  #pragma unroll
  for (int ct=0; ct<4; ct++){
    int c = col0 + ct*16 + lr;
    #pragma unroll
    for (int ks=0; ks<2; ks++){
      short8 b = *(const short8*)&Wbf[(size_t)c*HID + ks*32 + lk*8];
      #pragma unroll
      for (int rt=0; rt<2; rt++)
        acc[rt][ct] = __builtin_amdgcn_mfma_f32_16x16x32_bf16(b, a[rt][ks], acc[rt][ct], 0,0,0);
    }
  }
  // row = row0+rt*16+lr, cols = col0+ct*16+lk*4+{0..3}: one 8B store per (rt,ct)
  #pragma unroll
  for (int rt=0; rt<2; rt++){
    int r = row0 + rt*16 + lr;
    if (r < NN){
      #pragma unroll
      for (int ct=0; ct<4; ct++){
        int cq = col0 + ct*16 + (lk<<2);
        float4 bv = ld4(bias + cq);
        unsigned lo = (unsigned)f2h(acc[rt][ct][0]+bv.x) | ((unsigned)f2h(acc[rt][ct][1]+bv.y)<<16);
        unsigned hi = (unsigned)f2h(acc[rt][ct][2]+bv.z) | ((unsigned)f2h(acc[rt][ct][3]+bv.w)<<16);
        uint2 o = {lo, hi};
        *(uint2*)&out[(size_t)r*512 + cq] = o;
      }
    }
  }
}

// ---------------- fused GATv2 aggregation + head-mean + LN + residual + relu ----------------
// round-11 structure (frozen); bf16-only intermediate h
#define EDGE_BODY(UX, UY, A)                                                   \
  {                                                                            \
    h2 x2a = __builtin_bit_cast(h2, (UX));                                     \
    h2 x2b = __builtin_bit_cast(h2, (UY));                                     \
    h2 m2a = x2a + ((A)==0 ? xre0a : ((A)==1 ? xre1a : xre2a));                \
    h2 m2b = x2b + ((A)==0 ? xre0b : ((A)==1 ? xre1b : xre2b));                \
    h2 n2a = __builtin_bit_cast(h2, __builtin_bit_cast(unsigned, m2a) & 0x7FFF7FFFu); \
    h2 n2b = __builtin_bit_cast(h2, __builtin_bit_cast(unsigned, m2b) & 0x7FFF7FFFu); \
    float part = __builtin_amdgcn_fdot2(m2a, av6a, 0.f, false);                \
    part = __builtin_amdgcn_fdot2(m2b, av6b, part, false);                     \
    part = __builtin_amdgcn_fdot2(n2a, av4a, part, false);                     \
    part = __builtin_amdgcn_fdot2(n2b, av4b, part, false);                     \
    part = DPP_ADD(part, 0xB1);                                                \
    part = DPP_ADD(part, 0x4E);                                                \
    part = DPP_ADD(part, 0x124);                                               \
    part = DPP_ADD(part, 0x128);                                               \
    float p = exp2f(part);                                                     \
    den += p;                                                                  \
    ax = fmaf(p, (float)x2a.x, ax);                                            \
    ay = fmaf(p, (float)x2a.y, ay);                                            \
    az = fmaf(p, (float)x2b.x, az);                                            \
    aw = fmaf(p, (float)x2b.y, aw);                                            \
  }

__global__ __launch_bounds__(256) void agg_kernel(
    const unsigned short* __restrict__ xlr,
    const int* __restrict__ rowp, const int* __restrict__ csrp,
    const int* __restrict__ order,
    const float* __restrict__ ep_l, const float* __restrict__ att_l,
    const float* __restrict__ bias_l, const float* __restrict__ g_l, const float* __restrict__ b_l,
    unsigned short* __restrict__ hbf, float* __restrict__ out_last,
    int use_res, int do_relu, int last)
{
  int idx = (blockIdx.x << 2) | (threadIdx.x >> 6);
  int lane = threadIdx.x & 63;
  if (idx >= NN) return;
  int d = order[idx];
  int cb = lane << 2;

  uint2 xru = *(const uint2*)(xlr + ((size_t)d << 9) + 256 + cb);
  h2 xr2a = __builtin_bit_cast(h2, xru.x);
  h2 xr2b = __builtin_bit_cast(h2, xru.y);
  float xrf0 = (float)xr2a.x, xrf1 = (float)xr2a.y;
  float xrf2 = (float)xr2b.x, xrf3 = (float)xr2b.y;

  float4 ev0 = ld4(ep_l + cb);
  float4 ev1 = ld4(ep_l + HC + cb);
  float4 ev2 = ld4(ep_l + 2*HC + cb);
  h2 xre0a = {(_Float16)(xrf0+ev0.x), (_Float16)(xrf1+ev0.y)};
  h2 xre0b = {(_Float16)(xrf2+ev0.z), (_Float16)(xrf3+ev0.w)};
  h2 xre1a = {(_Float16)(xrf0+ev1.x), (_Float16)(xrf1+ev1.y)};
  h2 xre1b = {(_Float16)(xrf2+ev1.z), (_Float16)(xrf3+ev1.w)};
  h2 xre2a = {(_Float16)(xrf0+ev2.x), (_Float16)(xrf1+ev2.y)};
  h2 xre2b = {(_Float16)(xrf2+ev2.z), (_Float16)(xrf3+ev2.w)};

  float4 av = ld4(att_l + cb);
  const float K6 = 0.6f*1.44269504f, K4 = 0.4f*1.44269504f;
  h2 av6a = {(_Float16)(av.x*K6), (_Float16)(av.y*K6)};
  h2 av6b = {(_Float16)(av.z*K6), (_Float16)(av.w*K6)};
  h2 av4a = {(_Float16)(av.x*K4), (_Float16)(av.y*K4)};
  h2 av4b = {(_Float16)(av.z*K4), (_Float16)(av.w*K4)};

  float den = 0.f;
  float ax=0.f, ay=0.f, az=0.f, aw=0.f;

  int beg = rowp[d], stop = rowp[d+1];
  int i = beg;
  for (; i + 4 <= stop; i += 4){
    int p0 = csrp[i], p1 = csrp[i+1], p2 = csrp[i+2], p3 = csrp[i+3];
    uint2 u0 = *(const uint2*)(xlr + ((size_t)(p0 & 0xFFFF) << 9) + cb);
    uint2 u1 = *(const uint2*)(xlr + ((size_t)(p1 & 0xFFFF) << 9) + cb);
    uint2 u2 = *(const uint2*)(xlr + ((size_t)(p2 & 0xFFFF) << 9) + cb);
    uint2 u3 = *(const uint2*)(xlr + ((size_t)(p3 & 0xFFFF) << 9) + cb);
    int a0 = p0 >> 16, a1 = p1 >> 16, a2 = p2 >> 16, a3 = p3 >> 16;
    EDGE_BODY(u0.x, u0.y, a0);
    EDGE_BODY(u1.x, u1.y, a1);
    EDGE_BODY(u2.x, u2.y, a2);
    EDGE_BODY(u3.x, u3.y, a3);
  }
  if (i + 2 <= stop){
    int p0 = csrp[i], p1 = csrp[i+1];
    uint2 u0 = *(const uint2*)(xlr + ((size_t)(p0 & 0xFFFF) << 9) + cb);
    uint2 u1 = *(const uint2*)(xlr + ((size_t)(p1 & 0xFFFF) << 9) + cb);
    int a0 = p0 >> 16, a1 = p1 >> 16;
    EDGE_BODY(u0.x, u0.y, a0);
    EDGE_BODY(u1.x, u1.y, a1);
    i += 2;
  }
  if (i < stop){
    int p0 = csrp[i];
    uint2 u0 = *(const uint2*)(xlr + ((size_t)(p0 & 0xFFFF) << 9) + cb);
    int a0 = p0 >> 16;
    EDGE_BODY(u0.x, u0.y, a0);
  }

  float inv = (den > 0.f) ? 1.f/den : 0.f;
  ax *= inv; ay *= inv; az *= inv; aw *= inv;

  ax += __shfl_xor(ax,16); ay += __shfl_xor(ay,16); az += __shfl_xor(az,16); aw += __shfl_xor(aw,16);
  ax += __shfl_xor(ax,32); ay += __shfl_xor(ay,32); az += __shfl_xor(az,32); aw += __shfl_xor(aw,32);

  int cc = (lane & 15) << 2;
  float4 bv = ld4(bias_l + cc);
  float h0 = ax*0.25f + bv.x;
  float h1 = ay*0.25f + bv.y;
  float h2v = az*0.25f + bv.z;
  float h3 = aw*0.25f + bv.w;

  float s1 = h0+h1+h2v+h3;
  float s2 = h0*h0 + h1*h1 + h2v*h2v + h3*h3;
  s1 += __shfl_xor(s1,1); s2 += __shfl_xor(s2,1);
  s1 += __shfl_xor(s1,2); s2 += __shfl_xor(s2,2);
  s1 += __shfl_xor(s1,4); s2 += __shfl_xor(s2,4);
  s1 += __shfl_xor(s1,8); s2 += __shfl_xor(s2,8);
  float mu  = s1 * (1.f/64.f);
  float var = fmaxf(s2*(1.f/64.f) - mu*mu, 0.f);
  float rstd = rsqrtf(var + 1e-5f);
  float4 gv  = ld4(g_l + cc);
  float4 bbv = ld4(b_l + cc);
  float r0 = (h0-mu)*rstd*gv.x + bbv.x;
  float r1 = (h1-mu)*rstd*gv.y + bbv.y;
  float r2 = (h2v-mu)*rstd*gv.z + bbv.z;
  float r3 = (h3-mu)*rstd*gv.w + bbv.w;
  if (use_res){
    ushort4 hv = *(const ushort4*)(hbf + (size_t)d*HID + cc);
    r0 += b2f(hv.x); r1 += b2f(hv.y); r2 += b2f(hv.z); r3 += b2f(hv.w);
  }
  if (do_relu){
    r0 = fmaxf(r0, 0.f); r1 = fmaxf(r1, 0.f);
    r2 = fmaxf(r2, 0.f); r3 = fmaxf(r3, 0.f);
  }
  if (lane < 16){
    if (last){
      float4 o = {r0, r1, r2, r3};
      *(float4*)(out_last + (size_t)d*HID + cc) = o;
    } else {
      ushort4 obv = {f2b(r0), f2b(r1), f2b(r2), f2b(r3)};
      *(ushort4*)(hbf + (size_t)d*HID + cc) = obv;
    }
  }
}

// ---------------- launch ----------------
extern "C" void kernel_launch(void* const* d_in, const int* in_sizes, int n_in,
                              void* d_out, int out_size, void* d_ws, size_t ws_size,
                              hipStream_t stream){
  const float* x    = (const float*)d_in[0];
  const int*   ei   = (const int*)d_in[1];
  const int*   ea   = (const int*)d_in[2];
  const float* inW  = (const float*)d_in[3];
  const float* inb  = (const float*)d_in[4];
  const float* etab = (const float*)d_in[5];
  const float* Wl   = (const float*)d_in[6];
  const float* bl   = (const float*)d_in[7];
  const float* Wr   = (const float*)d_in[8];
  const float* br   = (const float*)d_in[9];
  const float* We   = (const float*)d_in[10];
  const float* att  = (const float*)d_in[11];
  const float* ob   = (const float*)d_in[12];
  const float* lg   = (const float*)d_in[13];
  const float* lb   = (const float*)d_in[14];

  char* w = (char*)d_ws;
  size_t off = 0;
  auto alloc = [&](size_t bytes)->char*{
    char* p = w + off;
    off = (off + bytes + 255) & ~(size_t)255;
    return p;
  };
  unsigned short* hbf = (unsigned short*)alloc((size_t)NN*HID*2);
  unsigned short* xlr = (unsigned short*)alloc((size_t)NN*512*2);
  unsigned short* inW_bf = (unsigned short*)alloc((size_t)HID*INDIM*2);
  unsigned short* Wlr    = (unsigned short*)alloc((size_t)NL*512*HID*2);
  float* blr   = (float*)alloc((size_t)NL*512*4);
  float* ep    = (float*)alloc((size_t)NL*3*HC*4);
  int*   deg   = (int*)alloc((size_t)NN*4);
  int*   bsum  = (int*)alloc((size_t)SCAN_NB*4);
  int*   rowp  = (int*)alloc((size_t)(NN+1)*4);
  int*   csrp  = (int*)alloc((size_t)NE*4);
  int*   gbin  = (int*)alloc((size_t)NBIN*BINPAD*4);
  int*   bbase = (int*)alloc((size_t)SCAN_NB*NBIN*4);
  int*   order = (int*)alloc((size_t)NN*4);

  hipMemsetAsync(deg, 0, (size_t)NN*4, stream);

  const int* srcp = ei;
  const int* dstp = ei + NE;
  deg_kernel<<<dim3((NE+255)/256), dim3(256), 0, stream>>>(dstp, deg, gbin);
  scanA_kernel<<<dim3(SCAN_NB), dim3(256), 0, stream>>>(deg, bsum, gbin, bbase);
  scanB_kernel<<<dim3(1), dim3(256), 0, stream>>>(bsum, gbin);
  scanC_kernel<<<dim3(SCAN_NB), dim3(256), 0, stream>>>(deg, bsum, gbin, bbase, rowp, order);
  scatter_kernel<<<dim3((NE+255)/256), dim3(256), 0, stream>>>(srcp, dstp, ea, rowp, deg, csrp);
  prep_kernel<<<dim3(64), dim3(256), 0, stream>>>(inW, Wl, Wr, bl, br, etab, We, inW_bf, Wlr, blr, ep);

  const int MB = (NN + 127)/128;   // 391
  gemm_in_kernel<<<dim3(MB), dim3(256), 0, stream>>>(x, inW_bf, inb, hbf);

  for (int l=0; l<NL; l++){
    gemm_lr_kernel<<<dim3(MB,8), dim3(256), 0, stream>>>(
        hbf, Wlr + (size_t)l*512*HID, blr + (size_t)l*512, xlr);
    agg_kernel<<<dim3((NN+3)/4), dim3(256), 0, stream>>>(
        xlr, rowp, csrp, order,
        ep + (size_t)l*3*HC, att + (size_t)l*HC,
        ob + (size_t)l*HID, lg + (size_t)l*HID, lb + (size_t)l*HID,
        hbf, (float*)d_out,
        (l >= NL/2) ? 1 : 0, (l < NL-1) ? 1 : 0, (l == NL-1) ? 1 : 0);
  }
}

// Round 15
// 511.517 us; speedup vs baseline: 1.1170x; 1.0230x over previous
//
#include <hip/hip_runtime.h>
#include <hip/hip_bf16.h>
#include <hip/hip_fp16.h>
#include <math.h>

#define NN 50000
#define NE 400000
#define INDIM 128
#define HID 64
#define HC 256
#define NL 6
#define ED 16
#define SCAN_B 256
#define SCAN_NB ((NN + SCAN_B - 1)/SCAN_B)   // 196
#define NBIN 64
#define BINPAD 16

typedef __attribute__((ext_vector_type(8))) short short8;
typedef __attribute__((ext_vector_type(4))) float f32x4;
typedef _Float16 h2 __attribute__((ext_vector_type(2)));

static __device__ __forceinline__ float4 ld4(const float* p){ return *(const float4*)p; }
static __device__ __forceinline__ unsigned short f2b(float x){
  __hip_bfloat16 h = __float2bfloat16(x);
  return *(unsigned short*)&h;
}
static __device__ __forceinline__ unsigned short f2h(float x){
  __half h = __float2half(x);
  return *(unsigned short*)&h;
}
static __device__ __forceinline__ float b2f(unsigned short u){
  return __builtin_bit_cast(float, (unsigned)u << 16);
}

// DPP lane combine (pure VALU): 0xB1=xor1, 0x4E=xor2, 0x124=row_ror:4, 0x128=row_ror:8
#define DPP_ADD(X, CTRL) \
  ((X) + __builtin_bit_cast(float, __builtin_amdgcn_update_dpp(0, __builtin_bit_cast(int, (X)), (CTRL), 0xF, 0xF, true)))

// ---------------- prep: bf16 weights + Wl/Wr fusion + ep_table ----------------
__global__ void prep_kernel(const float* __restrict__ inW, const float* __restrict__ Wl,
                            const float* __restrict__ Wr, const float* __restrict__ bl,
                            const float* __restrict__ br, const float* __restrict__ etab,
                            const float* __restrict__ We,
                            unsigned short* __restrict__ inW_bf,
                            unsigned short* __restrict__ Wlr,
                            float* __restrict__ blr, float* __restrict__ ep){
  int i = blockIdx.x*blockDim.x + threadIdx.x;
  if (i < HID*INDIM) inW_bf[i] = f2b(inW[i]);
  if (i < NL*512){
    int l = i / 512, c = i % 512;
    blr[i] = (c < HC) ? bl[l*HC + c] : br[l*HC + (c-HC)];
  }
  if (i < NL*3*HC){
    int l  = i / (3*HC);
    int a  = (i / HC) % 3;
    int hc = i % HC;
    const float* wrow = We + ((size_t)l*HC + hc)*ED;
    const float* erow = etab + a*ED;
    float s = 0.f;
    #pragma unroll
    for (int k=0;k<ED;k++) s += erow[k]*wrow[k];
    ep[i] = s;
  }
  int tot = NL*512*HID;
  for (int j = i; j < tot; j += gridDim.x*blockDim.x){
    int l = j / (512*HID);
    int c = (j / HID) % 512;
    int k = j % HID;
    float v = (c < HC) ? Wl[((size_t)l*HC + c)*HID + k]
                       : Wr[((size_t)l*HC + (c-HC))*HID + k];
    Wlr[j] = f2b(v);
  }
}

// ---------------- CSR build + degree-sort (fused pre-pass) ----------------
__global__ void deg_kernel(const int* __restrict__ dst, int* __restrict__ deg,
                           int* __restrict__ gbin){
  int e = blockIdx.x*blockDim.x + threadIdx.x;
  if (e < NBIN*BINPAD) gbin[e] = 0;
  if (e < NE) atomicAdd(&deg[dst[e]], 1);
}

__global__ void scanA_kernel(const int* __restrict__ deg, int* __restrict__ bsum,
                             int* __restrict__ gbin, int* __restrict__ bbase){
  __shared__ int lh[NBIN];
  __shared__ int ws[4];
  int t = threadIdx.x, b = blockIdx.x;
  if (t < NBIN) lh[t] = 0;
  __syncthreads();
  int i = b*SCAN_B + t;
  int v = (i < NN) ? deg[i] : 0;
  if (i < NN){
    int dg = v > 63 ? 63 : v;
    atomicAdd(&lh[63 - dg], 1);
  }
  int s = v;
  #pragma unroll
  for (int o=1;o<64;o<<=1) s += __shfl_xor(s,o);
  if ((t&63)==0) ws[t>>6] = s;
  __syncthreads();
  if (t==0) bsum[b] = ws[0]+ws[1]+ws[2]+ws[3];
  if (t < NBIN){
    int c = lh[t];
    bbase[b*NBIN + t] = c ? atomicAdd(&gbin[t*BINPAD], c) : 0;
  }
}

__global__ void scanB_kernel(int* __restrict__ bsum, int* __restrict__ gbin){
  __shared__ int sh[256];
  int t = threadIdx.x;
  int v = (t < SCAN_NB) ? bsum[t] : 0;
  sh[t] = v;
  __syncthreads();
  for (int o=1;o<256;o<<=1){
    int u = (t>=o)?sh[t-o]:0;
    __syncthreads();
    sh[t]+=u;
    __syncthreads();
  }
  int excl = (t==0)?0:sh[t-1];
  if (t < SCAN_NB) bsum[t] = excl;
  if (t < NBIN){
    int v2 = gbin[t*BINPAD];
    int s2 = v2;
    #pragma unroll
    for (int o=1;o<64;o<<=1){
      int u = __shfl_up(s2, o);
      if (t >= o) s2 += u;
    }
    gbin[t*BINPAD] = s2 - v2;
  }
}

__global__ void scanC_kernel(const int* __restrict__ deg, const int* __restrict__ bsum,
                             const int* __restrict__ gbin, const int* __restrict__ bbase,
                             int* __restrict__ rowp, int* __restrict__ order){
  __shared__ int sh[256];
  __shared__ int lc[NBIN];
  int t = threadIdx.x, b = blockIdx.x;
  if (t < NBIN) lc[t] = 0;
  int i = b*SCAN_B + t;
  int v = (i<NN)?deg[i]:0;
  sh[t]=v;
  __syncthreads();
  for (int o=1;o<256;o<<=1){
    int u=(t>=o)?sh[t-o]:0;
    __syncthreads();
    sh[t]+=u;
    __syncthreads();
  }
  if (i < NN) rowp[i] = bsum[b] + sh[t] - v;
  if (i == 0) rowp[NN] = NE;
  if (i < NN){
    int dg = v > 63 ? 63 : v;
    int bin = 63 - dg;
    int r = atomicAdd(&lc[bin], 1);
    order[gbin[bin*BINPAD] + bbase[b*NBIN + bin] + r] = i;
  }
}

__global__ void scatter_kernel(const int* __restrict__ src, const int* __restrict__ dst,
                               const int* __restrict__ attr, const int* __restrict__ rowp,
                               int* __restrict__ deg, int* __restrict__ csrp){
  int e = blockIdx.x*blockDim.x + threadIdx.x;
  if (e >= NE) return;
  int d = dst[e];
  int pos = rowp[d] + atomicSub(&deg[d], 1) - 1;
  csrp[pos] = src[e] | (attr[e] << 16);
}

// ---------------- input GEMM: hbf = bf16(x @ inW.T + b), swapped-operand MFMA ----------------
__global__ __launch_bounds__(256) void gemm_in_kernel(
    const float* __restrict__ X, const unsigned short* __restrict__ Wbf,
    const float* __restrict__ bias, unsigned short* __restrict__ hbf)
{
  int wid = threadIdx.x >> 6, lane = threadIdx.x & 63;
  int row0 = blockIdx.x*128 + wid*32;
  int lr = lane & 15, lk = lane >> 4;
  short8 a[2][4];
  #pragma unroll
  for (int rt=0; rt<2; rt++){
    int r = row0 + rt*16 + lr; if (r >= NN) r = NN-1;
    const float* rp = X + (size_t)r*INDIM;
    #pragma unroll
    for (int ks=0; ks<4; ks++){
      const float* p = rp + ks*32 + lk*8;
      float4 u = ld4(p), v = ld4(p+4);
      short8 t;
      t[0]=(short)f2b(u.x); t[1]=(short)f2b(u.y); t[2]=(short)f2b(u.z); t[3]=(short)f2b(u.w);
      t[4]=(short)f2b(v.x); t[5]=(short)f2b(v.y); t[6]=(short)f2b(v.z); t[7]=(short)f2b(v.w);
      a[rt][ks] = t;
    }
  }
  f32x4 acc[2][4] = {};
  #pragma unroll
  for (int ct=0; ct<4; ct++){
    int c = ct*16 + lr;
    #pragma unroll
    for (int ks=0; ks<4; ks++){
      short8 b = *(const short8*)&Wbf[(size_t)c*INDIM + ks*32 + lk*8];
      #pragma unroll
      for (int rt=0; rt<2; rt++)
        acc[rt][ct] = __builtin_amdgcn_mfma_f32_16x16x32_bf16(b, a[rt][ks], acc[rt][ct], 0,0,0);
    }
  }
  #pragma unroll
  for (int rt=0; rt<2; rt++){
    int r = row0 + rt*16 + lr;
    if (r < NN){
      #pragma unroll
      for (int ct=0; ct<4; ct++){
        int cq = ct*16 + (lk<<2);
        float4 bv = ld4(bias + cq);
        ushort4 o = { f2b(acc[rt][ct][0]+bv.x), f2b(acc[rt][ct][1]+bv.y),
                      f2b(acc[rt][ct][2]+bv.z), f2b(acc[rt][ct][3]+bv.w) };
        *(ushort4*)&hbf[(size_t)r*HID + cq] = o;
      }
    }
  }
}

// ---------------- layer GEMM: xlr = h_bf @ Wlr.T + blr ([NN][512] fp16) ----------------
__global__ __launch_bounds__(256) void gemm_lr_kernel(
    const unsigned short* __restrict__ Abf, const unsigned short* __restrict__ Wbf,
    const float* __restrict__ bias, unsigned short* __restrict__ out)
{
  int wid = threadIdx.x >> 6, lane = threadIdx.x & 63;
  int row0 = blockIdx.x*128 + wid*32;
  int col0 = blockIdx.y*64;
  int lr = lane & 15, lk = lane >> 4;
  short8 a[2][2];
  #pragma unroll
  for (int rt=0; rt<2; rt++){
    int r = row0 + rt*16 + lr; if (r >= NN) r = NN-1;
    #pragma unroll
    for (int ks=0; ks<2; ks++)
      a[rt][ks] = *(const short8*)&Abf[(size_t)r*HID + ks*32 + lk*8];
  }
  f32x4 acc[2][4] = {};
  #pragma unroll
  for (int ct=0; ct<4; ct++){
    int c = col0 + ct*16 + lr;
    #pragma unroll
    for (int ks=0; ks<2; ks++){
      short8 b = *(const short8*)&Wbf[(size_t)c*HID + ks*32 + lk*8];
      #pragma unroll
      for (int rt=0; rt<2; rt++)
        acc[rt][ct] = __builtin_amdgcn_mfma_f32_16x16x32_bf16(b, a[rt][ks], acc[rt][ct], 0,0,0);
    }
  }
  #pragma unroll
  for (int rt=0; rt<2; rt++){
    int r = row0 + rt*16 + lr;
    if (r < NN){
      #pragma unroll
      for (int ct=0; ct<4; ct++){
        int cq = col0 + ct*16 + (lk<<2);
        float4 bv = ld4(bias + cq);
        unsigned lo = (unsigned)f2h(acc[rt][ct][0]+bv.x) | ((unsigned)f2h(acc[rt][ct][1]+bv.y)<<16);
        unsigned hi = (unsigned)f2h(acc[rt][ct][2]+bv.z) | ((unsigned)f2h(acc[rt][ct][3]+bv.w)<<16);
        uint2 o = {lo, hi};
        *(uint2*)&out[(size_t)r*512 + cq] = o;
      }
    }
  }
}

// ---------------- fused GATv2 aggregation + head-mean + LN + residual + relu ----------------
// round-15: raw v_exp_f32 (skip ocml guard; logits bounded) + fp16 packed accumulation
// (1 cvt + 2 v_pk_fma_f16 per edge instead of 4 cvt + 4 fma)
#define EDGE_BODY(UX, UY, A)                                                   \
  {                                                                            \
    h2 x2a = __builtin_bit_cast(h2, (UX));                                     \
    h2 x2b = __builtin_bit_cast(h2, (UY));                                     \
    h2 m2a = x2a + ((A)==0 ? xre0a : ((A)==1 ? xre1a : xre2a));                \
    h2 m2b = x2b + ((A)==0 ? xre0b : ((A)==1 ? xre1b : xre2b));                \
    h2 n2a = __builtin_bit_cast(h2, __builtin_bit_cast(unsigned, m2a) & 0x7FFF7FFFu); \
    h2 n2b = __builtin_bit_cast(h2, __builtin_bit_cast(unsigned, m2b) & 0x7FFF7FFFu); \
    float part = __builtin_amdgcn_fdot2(m2a, av6a, 0.f, false);                \
    part = __builtin_amdgcn_fdot2(m2b, av6b, part, false);                     \
    part = __builtin_amdgcn_fdot2(n2a, av4a, part, false);                     \
    part = __builtin_amdgcn_fdot2(n2b, av4b, part, false);                     \
    part = DPP_ADD(part, 0xB1);                                                \
    part = DPP_ADD(part, 0x4E);                                                \
    part = DPP_ADD(part, 0x124);                                               \
    part = DPP_ADD(part, 0x128);                                               \
    float p;                                                                   \
    asm("v_exp_f32 %0, %1" : "=v"(p) : "v"(part));                             \
    den += p;                                                                  \
    _Float16 ph = (_Float16)p;                                                 \
    h2 ph2 = {ph, ph};                                                         \
    acc2a = x2a * ph2 + acc2a;                                                 \
    acc2b = x2b * ph2 + acc2b;                                                 \
  }

__global__ __launch_bounds__(256) void agg_kernel(
    const unsigned short* __restrict__ xlr,
    const int* __restrict__ rowp, const int* __restrict__ csrp,
    const int* __restrict__ order,
    const float* __restrict__ ep_l, const float* __restrict__ att_l,
    const float* __restrict__ bias_l, const float* __restrict__ g_l, const float* __restrict__ b_l,
    unsigned short* __restrict__ hbf, float* __restrict__ out_last,
    int use_res, int do_relu, int last)
{
  int idx = (blockIdx.x << 2) | (threadIdx.x >> 6);
  int lane = threadIdx.x & 63;
  if (idx >= NN) return;
  int d = order[idx];
  int cb = lane << 2;

  uint2 xru = *(const uint2*)(xlr + ((size_t)d << 9) + 256 + cb);
  h2 xr2a = __builtin_bit_cast(h2, xru.x);
  h2 xr2b = __builtin_bit_cast(h2, xru.y);
  float xrf0 = (float)xr2a.x, xrf1 = (float)xr2a.y;
  float xrf2 = (float)xr2b.x, xrf3 = (float)xr2b.y;

  float4 ev0 = ld4(ep_l + cb);
  float4 ev1 = ld4(ep_l + HC + cb);
  float4 ev2 = ld4(ep_l + 2*HC + cb);
  h2 xre0a = {(_Float16)(xrf0+ev0.x), (_Float16)(xrf1+ev0.y)};
  h2 xre0b = {(_Float16)(xrf2+ev0.z), (_Float16)(xrf3+ev0.w)};
  h2 xre1a = {(_Float16)(xrf0+ev1.x), (_Float16)(xrf1+ev1.y)};
  h2 xre1b = {(_Float16)(xrf2+ev1.z), (_Float16)(xrf3+ev1.w)};
  h2 xre2a = {(_Float16)(xrf0+ev2.x), (_Float16)(xrf1+ev2.y)};
  h2 xre2b = {(_Float16)(xrf2+ev2.z), (_Float16)(xrf3+ev2.w)};

  float4 av = ld4(att_l + cb);
  const float K6 = 0.6f*1.44269504f, K4 = 0.4f*1.44269504f;
  h2 av6a = {(_Float16)(av.x*K6), (_Float16)(av.y*K6)};
  h2 av6b = {(_Float16)(av.z*K6), (_Float16)(av.w*K6)};
  h2 av4a = {(_Float16)(av.x*K4), (_Float16)(av.y*K4)};
  h2 av4b = {(_Float16)(av.z*K4), (_Float16)(av.w*K4)};

  float den = 0.f;
  h2 acc2a = {(_Float16)0.f, (_Float16)0.f};
  h2 acc2b = {(_Float16)0.f, (_Float16)0.f};

  int beg = rowp[d], stop = rowp[d+1];
  int i = beg;
  for (; i + 4 <= stop; i += 4){
    int p0 = csrp[i], p1 = csrp[i+1], p2 = csrp[i+2], p3 = csrp[i+3];
    uint2 u0 = *(const uint2*)(xlr + ((size_t)(p0 & 0xFFFF) << 9) + cb);
    uint2 u1 = *(const uint2*)(xlr + ((size_t)(p1 & 0xFFFF) << 9) + cb);
    uint2 u2 = *(const uint2*)(xlr + ((size_t)(p2 & 0xFFFF) << 9) + cb);
    uint2 u3 = *(const uint2*)(xlr + ((size_t)(p3 & 0xFFFF) << 9) + cb);
    int a0 = p0 >> 16, a1 = p1 >> 16, a2 = p2 >> 16, a3 = p3 >> 16;
    EDGE_BODY(u0.x, u0.y, a0);
    EDGE_BODY(u1.x, u1.y, a1);
    EDGE_BODY(u2.x, u2.y, a2);
    EDGE_BODY(u3.x, u3.y, a3);
  }
  if (i + 2 <= stop){
    int p0 = csrp[i], p1 = csrp[i+1];
    uint2 u0 = *(const uint2*)(xlr + ((size_t)(p0 & 0xFFFF) << 9) + cb);
    uint2 u1 = *(const uint2*)(xlr + ((size_t)(p1 & 0xFFFF) << 9) + cb);
    int a0 = p0 >> 16, a1 = p1 >> 16;
    EDGE_BODY(u0.x, u0.y, a0);
    EDGE_BODY(u1.x, u1.y, a1);
    i += 2;
  }
  if (i < stop){
    int p0 = csrp[i];
    uint2 u0 = *(const uint2*)(xlr + ((size_t)(p0 & 0xFFFF) << 9) + cb);
    int a0 = p0 >> 16;
    EDGE_BODY(u0.x, u0.y, a0);
  }

  float ax = (float)acc2a.x, ay = (float)acc2a.y;
  float az = (float)acc2b.x, aw = (float)acc2b.y;
  float inv = (den > 0.f) ? 1.f/den : 0.f;
  ax *= inv; ay *= inv; az *= inv; aw *= inv;

  ax += __shfl_xor(ax,16); ay += __shfl_xor(ay,16); az += __shfl_xor(az,16); aw += __shfl_xor(aw,16);
  ax += __shfl_xor(ax,32); ay += __shfl_xor(ay,32); az += __shfl_xor(az,32); aw += __shfl_xor(aw,32);

  int cc = (lane & 15) << 2;
  float4 bv = ld4(bias_l + cc);
  float h0 = ax*0.25f + bv.x;
  float h1 = ay*0.25f + bv.y;
  float h2v = az*0.25f + bv.z;
  float h3 = aw*0.25f + bv.w;

  float s1 = h0+h1+h2v+h3;
  float s2 = h0*h0 + h1*h1 + h2v*h2v + h3*h3;
  s1 += __shfl_xor(s1,1); s2 += __shfl_xor(s2,1);
  s1 += __shfl_xor(s1,2); s2 += __shfl_xor(s2,2);
  s1 += __shfl_xor(s1,4); s2 += __shfl_xor(s2,4);
  s1 += __shfl_xor(s1,8); s2 += __shfl_xor(s2,8);
  float mu  = s1 * (1.f/64.f);
  float var = fmaxf(s2*(1.f/64.f) - mu*mu, 0.f);
  float rstd = rsqrtf(var + 1e-5f);
  float4 gv  = ld4(g_l + cc);
  float4 bbv = ld4(b_l + cc);
  float r0 = (h0-mu)*rstd*gv.x + bbv.x;
  float r1 = (h1-mu)*rstd*gv.y + bbv.y;
  float r2 = (h2v-mu)*rstd*gv.z + bbv.z;
  float r3 = (h3-mu)*rstd*gv.w + bbv.w;
  if (use_res){
    ushort4 hv = *(const ushort4*)(hbf + (size_t)d*HID + cc);
    r0 += b2f(hv.x); r1 += b2f(hv.y); r2 += b2f(hv.z); r3 += b2f(hv.w);
  }
  if (do_relu){
    r0 = fmaxf(r0, 0.f); r1 = fmaxf(r1, 0.f);
    r2 = fmaxf(r2, 0.f); r3 = fmaxf(r3, 0.f);
  }
  if (lane < 16){
    if (last){
      float4 o = {r0, r1, r2, r3};
      *(float4*)(out_last + (size_t)d*HID + cc) = o;
    } else {
      ushort4 obv = {f2b(r0), f2b(r1), f2b(r2), f2b(r3)};
      *(ushort4*)(hbf + (size_t)d*HID + cc) = obv;
    }
  }
}

// ---------------- launch ----------------
extern "C" void kernel_launch(void* const* d_in, const int* in_sizes, int n_in,
                              void* d_out, int out_size, void* d_ws, size_t ws_size,
                              hipStream_t stream){
  const float* x    = (const float*)d_in[0];
  const int*   ei   = (const int*)d_in[1];
  const int*   ea   = (const int*)d_in[2];
  const float* inW  = (const float*)d_in[3];
  const float* inb  = (const float*)d_in[4];
  const float* etab = (const float*)d_in[5];
  const float* Wl   = (const float*)d_in[6];
  const float* bl   = (const float*)d_in[7];
  const float* Wr   = (const float*)d_in[8];
  const float* br   = (const float*)d_in[9];
  const float* We   = (const float*)d_in[10];
  const float* att  = (const float*)d_in[11];
  const float* ob   = (const float*)d_in[12];
  const float* lg   = (const float*)d_in[13];
  const float* lb   = (const float*)d_in[14];

  char* w = (char*)d_ws;
  size_t off = 0;
  auto alloc = [&](size_t bytes)->char*{
    char* p = w + off;
    off = (off + bytes + 255) & ~(size_t)255;
    return p;
  };
  unsigned short* hbf = (unsigned short*)alloc((size_t)NN*HID*2);
  unsigned short* xlr = (unsigned short*)alloc((size_t)NN*512*2);
  unsigned short* inW_bf = (unsigned short*)alloc((size_t)HID*INDIM*2);
  unsigned short* Wlr    = (unsigned short*)alloc((size_t)NL*512*HID*2);
  float* blr   = (float*)alloc((size_t)NL*512*4);
  float* ep    = (float*)alloc((size_t)NL*3*HC*4);
  int*   deg   = (int*)alloc((size_t)NN*4);
  int*   bsum  = (int*)alloc((size_t)SCAN_NB*4);
  int*   rowp  = (int*)alloc((size_t)(NN+1)*4);
  int*   csrp  = (int*)alloc((size_t)NE*4);
  int*   gbin  = (int*)alloc((size_t)NBIN*BINPAD*4);
  int*   bbase = (int*)alloc((size_t)SCAN_NB*NBIN*4);
  int*   order = (int*)alloc((size_t)NN*4);

  hipMemsetAsync(deg, 0, (size_t)NN*4, stream);

  const int* srcp = ei;
  const int* dstp = ei + NE;
  deg_kernel<<<dim3((NE+255)/256), dim3(256), 0, stream>>>(dstp, deg, gbin);
  scanA_kernel<<<dim3(SCAN_NB), dim3(256), 0, stream>>>(deg, bsum, gbin, bbase);
  scanB_kernel<<<dim3(1), dim3(256), 0, stream>>>(bsum, gbin);
  scanC_kernel<<<dim3(SCAN_NB), dim3(256), 0, stream>>>(deg, bsum, gbin, bbase, rowp, order);
  scatter_kernel<<<dim3((NE+255)/256), dim3(256), 0, stream>>>(srcp, dstp, ea, rowp, deg, csrp);
  prep_kernel<<<dim3(64), dim3(256), 0, stream>>>(inW, Wl, Wr, bl, br, etab, We, inW_bf, Wlr, blr, ep);

  const int MB = (NN + 127)/128;   // 391
  gemm_in_kernel<<<dim3(MB), dim3(256), 0, stream>>>(x, inW_bf, inb, hbf);

  for (int l=0; l<NL; l++){
    gemm_lr_kernel<<<dim3(MB,8), dim3(256), 0, stream>>>(
        hbf, Wlr + (size_t)l*512*HID, blr + (size_t)l*512, xlr);
    agg_kernel<<<dim3((NN+3)/4), dim3(256), 0, stream>>>(
        xlr, rowp, csrp, order,
        ep + (size_t)l*3*HC, att + (size_t)l*HC,
        ob + (size_t)l*HID, lg + (size_t)l*HID, lb + (size_t)l*HID,
        hbf, (float*)d_out,
        (l >= NL/2) ? 1 : 0, (l < NL-1) ? 1 : 0, (l == NL-1) ? 1 : 0);
  }
}

// Round 16
// 493.351 us; speedup vs baseline: 1.1582x; 1.0368x over previous
//
#include <hip/hip_runtime.h>
#include <hip/hip_bf16.h>
#include <hip/hip_fp16.h>
#include <math.h>

#define NN 50000
#define NE 400000
#define INDIM 128
#define HID 64
#define HC 256
#define NL 6
#define ED 16
#define SCAN_B 256
#define SCAN_NB ((NN + SCAN_B - 1)/SCAN_B)   // 196
#define NBIN 64
#define BINPAD 16

typedef __attribute__((ext_vector_type(8))) short short8;
typedef __attribute__((ext_vector_type(4))) float f32x4;
typedef _Float16 h2 __attribute__((ext_vector_type(2)));

static __device__ __forceinline__ float4 ld4(const float* p){ return *(const float4*)p; }
static __device__ __forceinline__ unsigned short f2b(float x){
  __hip_bfloat16 h = __float2bfloat16(x);
  return *(unsigned short*)&h;
}
static __device__ __forceinline__ unsigned short f2h(float x){
  __half h = __float2half(x);
  return *(unsigned short*)&h;
}
static __device__ __forceinline__ float b2f(unsigned short u){
  return __builtin_bit_cast(float, (unsigned)u << 16);
}

// DPP lane combine (pure VALU): 0xB1=xor1, 0x4E=xor2, 0x124=row_ror:4, 0x128=row_ror:8
#define DPP_ADD(X, CTRL) \
  ((X) + __builtin_bit_cast(float, __builtin_amdgcn_update_dpp(0, __builtin_bit_cast(int, (X)), (CTRL), 0xF, 0xF, true)))

// ---------------- prep: bf16 weights + Wl/Wr fusion + ep_table ----------------
__global__ void prep_kernel(const float* __restrict__ inW, const float* __restrict__ Wl,
                            const float* __restrict__ Wr, const float* __restrict__ bl,
                            const float* __restrict__ br, const float* __restrict__ etab,
                            const float* __restrict__ We,
                            unsigned short* __restrict__ inW_bf,
                            unsigned short* __restrict__ Wlr,
                            float* __restrict__ blr, float* __restrict__ ep){
  int i = blockIdx.x*blockDim.x + threadIdx.x;
  if (i < HID*INDIM) inW_bf[i] = f2b(inW[i]);
  if (i < NL*512){
    int l = i / 512, c = i % 512;
    blr[i] = (c < HC) ? bl[l*HC + c] : br[l*HC + (c-HC)];
  }
  if (i < NL*3*HC){
    int l  = i / (3*HC);
    int a  = (i / HC) % 3;
    int hc = i % HC;
    const float* wrow = We + ((size_t)l*HC + hc)*ED;
    const float* erow = etab + a*ED;
    float s = 0.f;
    #pragma unroll
    for (int k=0;k<ED;k++) s += erow[k]*wrow[k];
    ep[i] = s;
  }
  int tot = NL*512*HID;
  for (int j = i; j < tot; j += gridDim.x*blockDim.x){
    int l = j / (512*HID);
    int c = (j / HID) % 512;
    int k = j % HID;
    float v = (c < HC) ? Wl[((size_t)l*HC + c)*HID + k]
                       : Wr[((size_t)l*HC + (c-HC))*HID + k];
    Wlr[j] = f2b(v);
  }
}

// ---------------- CSR build + degree-sort (fused pre-pass) ----------------
__global__ void deg_kernel(const int* __restrict__ dst, int* __restrict__ deg,
                           int* __restrict__ gbin){
  int e = blockIdx.x*blockDim.x + threadIdx.x;
  if (e < NBIN*BINPAD) gbin[e] = 0;
  if (e < NE) atomicAdd(&deg[dst[e]], 1);
}

__global__ void scanA_kernel(const int* __restrict__ deg, int* __restrict__ bsum,
                             int* __restrict__ gbin, int* __restrict__ bbase){
  __shared__ int lh[NBIN];
  __shared__ int ws[4];
  int t = threadIdx.x, b = blockIdx.x;
  if (t < NBIN) lh[t] = 0;
  __syncthreads();
  int i = b*SCAN_B + t;
  int v = (i < NN) ? deg[i] : 0;
  if (i < NN){
    int dg = v > 63 ? 63 : v;
    atomicAdd(&lh[63 - dg], 1);
  }
  int s = v;
  #pragma unroll
  for (int o=1;o<64;o<<=1) s += __shfl_xor(s,o);
  if ((t&63)==0) ws[t>>6] = s;
  __syncthreads();
  if (t==0) bsum[b] = ws[0]+ws[1]+ws[2]+ws[3];
  if (t < NBIN){
    int c = lh[t];
    bbase[b*NBIN + t] = c ? atomicAdd(&gbin[t*BINPAD], c) : 0;
  }
}

__global__ void scanB_kernel(int* __restrict__ bsum, int* __restrict__ gbin){
  __shared__ int sh[256];
  int t = threadIdx.x;
  int v = (t < SCAN_NB) ? bsum[t] : 0;
  sh[t] = v;
  __syncthreads();
  for (int o=1;o<256;o<<=1){
    int u = (t>=o)?sh[t-o]:0;
    __syncthreads();
    sh[t]+=u;
    __syncthreads();
  }
  int excl = (t==0)?0:sh[t-1];
  if (t < SCAN_NB) bsum[t] = excl;
  if (t < NBIN){
    int v2 = gbin[t*BINPAD];
    int s2 = v2;
    #pragma unroll
    for (int o=1;o<64;o<<=1){
      int u = __shfl_up(s2, o);
      if (t >= o) s2 += u;
    }
    gbin[t*BINPAD] = s2 - v2;
  }
}

__global__ void scanC_kernel(const int* __restrict__ deg, const int* __restrict__ bsum,
                             const int* __restrict__ gbin, const int* __restrict__ bbase,
                             int* __restrict__ rowp, int* __restrict__ order){
  __shared__ int sh[256];
  __shared__ int lc[NBIN];
  int t = threadIdx.x, b = blockIdx.x;
  if (t < NBIN) lc[t] = 0;
  int i = b*SCAN_B + t;
  int v = (i<NN)?deg[i]:0;
  sh[t]=v;
  __syncthreads();
  for (int o=1;o<256;o<<=1){
    int u=(t>=o)?sh[t-o]:0;
    __syncthreads();
    sh[t]+=u;
    __syncthreads();
  }
  if (i < NN) rowp[i] = bsum[b] + sh[t] - v;
  if (i == 0) rowp[NN] = NE;
  if (i < NN){
    int dg = v > 63 ? 63 : v;
    int bin = 63 - dg;
    int r = atomicAdd(&lc[bin], 1);
    order[gbin[bin*BINPAD] + bbase[b*NBIN + bin] + r] = i;
  }
}

__global__ void scatter_kernel(const int* __restrict__ src, const int* __restrict__ dst,
                               const int* __restrict__ attr, const int* __restrict__ rowp,
                               int* __restrict__ deg, int* __restrict__ csrp){
  int e = blockIdx.x*blockDim.x + threadIdx.x;
  if (e >= NE) return;
  int d = dst[e];
  int pos = rowp[d] + atomicSub(&deg[d], 1) - 1;
  csrp[pos] = src[e] | (attr[e] << 16);
}

// ---------------- input GEMM: hbf = bf16(x @ inW.T + b), swapped-operand MFMA ----------------
__global__ __launch_bounds__(256) void gemm_in_kernel(
    const float* __restrict__ X, const unsigned short* __restrict__ Wbf,
    const float* __restrict__ bias, unsigned short* __restrict__ hbf)
{
  int wid = threadIdx.x >> 6, lane = threadIdx.x & 63;
  int row0 = blockIdx.x*128 + wid*32;
  int lr = lane & 15, lk = lane >> 4;
  short8 a[2][4];
  #pragma unroll
  for (int rt=0; rt<2; rt++){
    int r = row0 + rt*16 + lr; if (r >= NN) r = NN-1;
    const float* rp = X + (size_t)r*INDIM;
    #pragma unroll
    for (int ks=0; ks<4; ks++){
      const float* p = rp + ks*32 + lk*8;
      float4 u = ld4(p), v = ld4(p+4);
      short8 t;
      t[0]=(short)f2b(u.x); t[1]=(short)f2b(u.y); t[2]=(short)f2b(u.z); t[3]=(short)f2b(u.w);
      t[4]=(short)f2b(v.x); t[5]=(short)f2b(v.y); t[6]=(short)f2b(v.z); t[7]=(short)f2b(v.w);
      a[rt][ks] = t;
    }
  }
  f32x4 acc[2][4] = {};
  #pragma unroll
  for (int ct=0; ct<4; ct++){
    int c = ct*16 + lr;
    #pragma unroll
    for (int ks=0; ks<4; ks++){
      short8 b = *(const short8*)&Wbf[(size_t)c*INDIM + ks*32 + lk*8];
      #pragma unroll
      for (int rt=0; rt<2; rt++)
        acc[rt][ct] = __builtin_amdgcn_mfma_f32_16x16x32_bf16(b, a[rt][ks], acc[rt][ct], 0,0,0);
    }
  }
  #pragma unroll
  for (int rt=0; rt<2; rt++){
    int r = row0 + rt*16 + lr;
    if (r < NN){
      #pragma unroll
      for (int ct=0; ct<4; ct++){
        int cq = ct*16 + (lk<<2);
        float4 bv = ld4(bias + cq);
        ushort4 o = { f2b(acc[rt][ct][0]+bv.x), f2b(acc[rt][ct][1]+bv.y),
                      f2b(acc[rt][ct][2]+bv.z), f2b(acc[rt][ct][3]+bv.w) };
        *(ushort4*)&hbf[(size_t)r*HID + cq] = o;
      }
    }
  }
}

// ---------------- layer GEMM: xlr = h_bf @ Wlr.T + blr ([NN][512] fp16) ----------------
__global__ __launch_bounds__(256) void gemm_lr_kernel(
    const unsigned short* __restrict__ Abf, const unsigned short* __restrict__ Wbf,
    const float* __restrict__ bias, unsigned short* __restrict__ out)
{
  int wid = threadIdx.x >> 6, lane = threadIdx.x & 63;
  int row0 = blockIdx.x*128 + wid*32;
  int col0 = blockIdx.y*64;
  int lr = lane & 15, lk = lane >> 4;
  short8 a[2][2];
  #pragma unroll
  for (int rt=0; rt<2; rt++){
    int r = row0 + rt*16 + lr; if (r >= NN) r = NN-1;
    #pragma unroll
    for (int ks=0; ks<2; ks++)
      a[rt][ks] = *(const short8*)&Abf[(size_t)r*HID + ks*32 + lk*8];
  }
  f32x4 acc[2][4] = {};
  #pragma unroll
  for (int ct=0; ct<4; ct++){
    int c = col0 + ct*16 + lr;
    #pragma unroll
    for (int ks=0; ks<2; ks++){
      short8 b = *(const short8*)&Wbf[(size_t)c*HID + ks*32 + lk*8];
      #pragma unroll
      for (int rt=0; rt<2; rt++)
        acc[rt][ct] = __builtin_amdgcn_mfma_f32_16x16x32_bf16(b, a[rt][ks], acc[rt][ct], 0,0,0);
    }
  }
  #pragma unroll
  for (int rt=0; rt<2; rt++){
    int r = row0 + rt*16 + lr;
    if (r < NN){
      #pragma unroll
      for (int ct=0; ct<4; ct++){
        int cq = col0 + ct*16 + (lk<<2);
        float4 bv = ld4(bias + cq);
        unsigned lo = (unsigned)f2h(acc[rt][ct][0]+bv.x) | ((unsigned)f2h(acc[rt][ct][1]+bv.y)<<16);
        unsigned hi = (unsigned)f2h(acc[rt][ct][2]+bv.z) | ((unsigned)f2h(acc[rt][ct][3]+bv.w)<<16);
        uint2 o = {lo, hi};
        *(uint2*)&out[(size_t)r*512 + cq] = o;
      }
    }
  }
}

// ---------------- fused GATv2 aggregation + head-mean + LN + residual + relu ----------------
// round-16: wave-uniform scalarization — d/beg/stop/csrp via readfirstlane (SGPR + s_load),
// 32-bit gather offsets (SGPR base + single v_add). Math identical to round 15.
#define EDGE_BODY(UX, UY, A)                                                   \
  {                                                                            \
    h2 x2a = __builtin_bit_cast(h2, (UX));                                     \
    h2 x2b = __builtin_bit_cast(h2, (UY));                                     \
    h2 m2a = x2a + ((A)==0 ? xre0a : ((A)==1 ? xre1a : xre2a));                \
    h2 m2b = x2b + ((A)==0 ? xre0b : ((A)==1 ? xre1b : xre2b));                \
    h2 n2a = __builtin_bit_cast(h2, __builtin_bit_cast(unsigned, m2a) & 0x7FFF7FFFu); \
    h2 n2b = __builtin_bit_cast(h2, __builtin_bit_cast(unsigned, m2b) & 0x7FFF7FFFu); \
    float part = __builtin_amdgcn_fdot2(m2a, av6a, 0.f, false);                \
    part = __builtin_amdgcn_fdot2(m2b, av6b, part, false);                     \
    part = __builtin_amdgcn_fdot2(n2a, av4a, part, false);                     \
    part = __builtin_amdgcn_fdot2(n2b, av4b, part, false);                     \
    part = DPP_ADD(part, 0xB1);                                                \
    part = DPP_ADD(part, 0x4E);                                                \
    part = DPP_ADD(part, 0x124);                                               \
    part = DPP_ADD(part, 0x128);                                               \
    float p;                                                                   \
    asm("v_exp_f32 %0, %1" : "=v"(p) : "v"(part));                             \
    den += p;                                                                  \
    _Float16 ph = (_Float16)p;                                                 \
    h2 ph2 = {ph, ph};                                                         \
    acc2a = x2a * ph2 + acc2a;                                                 \
    acc2b = x2b * ph2 + acc2b;                                                 \
  }

#define GOFF(P) ((((unsigned)(P) & 0xFFFFu) << 9) + (unsigned)cb)

__global__ __launch_bounds__(256) void agg_kernel(
    const unsigned short* __restrict__ xlr,
    const int* __restrict__ rowp, const int* __restrict__ csrp,
    const int* __restrict__ order,
    const float* __restrict__ ep_l, const float* __restrict__ att_l,
    const float* __restrict__ bias_l, const float* __restrict__ g_l, const float* __restrict__ b_l,
    unsigned short* __restrict__ hbf, float* __restrict__ out_last,
    int use_res, int do_relu, int last)
{
  int idx = (blockIdx.x << 2) | (threadIdx.x >> 6);
  int lane = threadIdx.x & 63;
  if (idx >= NN) return;
  int d = __builtin_amdgcn_readfirstlane(order[idx]);
  int cb = lane << 2;

  uint2 xru = *(const uint2*)(xlr + ((unsigned)d << 9) + 256u + (unsigned)cb);
  h2 xr2a = __builtin_bit_cast(h2, xru.x);
  h2 xr2b = __builtin_bit_cast(h2, xru.y);
  float xrf0 = (float)xr2a.x, xrf1 = (float)xr2a.y;
  float xrf2 = (float)xr2b.x, xrf3 = (float)xr2b.y;

  float4 ev0 = ld4(ep_l + cb);
  float4 ev1 = ld4(ep_l + HC + cb);
  float4 ev2 = ld4(ep_l + 2*HC + cb);
  h2 xre0a = {(_Float16)(xrf0+ev0.x), (_Float16)(xrf1+ev0.y)};
  h2 xre0b = {(_Float16)(xrf2+ev0.z), (_Float16)(xrf3+ev0.w)};
  h2 xre1a = {(_Float16)(xrf0+ev1.x), (_Float16)(xrf1+ev1.y)};
  h2 xre1b = {(_Float16)(xrf2+ev1.z), (_Float16)(xrf3+ev1.w)};
  h2 xre2a = {(_Float16)(xrf0+ev2.x), (_Float16)(xrf1+ev2.y)};
  h2 xre2b = {(_Float16)(xrf2+ev2.z), (_Float16)(xrf3+ev2.w)};

  float4 av = ld4(att_l + cb);
  const float K6 = 0.6f*1.44269504f, K4 = 0.4f*1.44269504f;
  h2 av6a = {(_Float16)(av.x*K6), (_Float16)(av.y*K6)};
  h2 av6b = {(_Float16)(av.z*K6), (_Float16)(av.w*K6)};
  h2 av4a = {(_Float16)(av.x*K4), (_Float16)(av.y*K4)};
  h2 av4b = {(_Float16)(av.z*K4), (_Float16)(av.w*K4)};

  float den = 0.f;
  h2 acc2a = {(_Float16)0.f, (_Float16)0.f};
  h2 acc2b = {(_Float16)0.f, (_Float16)0.f};

  int beg = __builtin_amdgcn_readfirstlane(rowp[d]);
  int stop = __builtin_amdgcn_readfirstlane(rowp[d+1]);
  int i = beg;
  for (; i + 4 <= stop; i += 4){
    int p0 = __builtin_amdgcn_readfirstlane(csrp[i]);
    int p1 = __builtin_amdgcn_readfirstlane(csrp[i+1]);
    int p2 = __builtin_amdgcn_readfirstlane(csrp[i+2]);
    int p3 = __builtin_amdgcn_readfirstlane(csrp[i+3]);
    uint2 u0 = *(const uint2*)(xlr + GOFF(p0));
    uint2 u1 = *(const uint2*)(xlr + GOFF(p1));
    uint2 u2 = *(const uint2*)(xlr + GOFF(p2));
    uint2 u3 = *(const uint2*)(xlr + GOFF(p3));
    int a0 = p0 >> 16, a1 = p1 >> 16, a2 = p2 >> 16, a3 = p3 >> 16;
    EDGE_BODY(u0.x, u0.y, a0);
    EDGE_BODY(u1.x, u1.y, a1);
    EDGE_BODY(u2.x, u2.y, a2);
    EDGE_BODY(u3.x, u3.y, a3);
  }
  if (i + 2 <= stop){
    int p0 = __builtin_amdgcn_readfirstlane(csrp[i]);
    int p1 = __builtin_amdgcn_readfirstlane(csrp[i+1]);
    uint2 u0 = *(const uint2*)(xlr + GOFF(p0));
    uint2 u1 = *(const uint2*)(xlr + GOFF(p1));
    int a0 = p0 >> 16, a1 = p1 >> 16;
    EDGE_BODY(u0.x, u0.y, a0);
    EDGE_BODY(u1.x, u1.y, a1);
    i += 2;
  }
  if (i < stop){
    int p0 = __builtin_amdgcn_readfirstlane(csrp[i]);
    uint2 u0 = *(const uint2*)(xlr + GOFF(p0));
    int a0 = p0 >> 16;
    EDGE_BODY(u0.x, u0.y, a0);
  }

  float ax = (float)acc2a.x, ay = (float)acc2a.y;
  float az = (float)acc2b.x, aw = (float)acc2b.y;
  float inv = (den > 0.f) ? 1.f/den : 0.f;
  ax *= inv; ay *= inv; az *= inv; aw *= inv;

  ax += __shfl_xor(ax,16); ay += __shfl_xor(ay,16); az += __shfl_xor(az,16); aw += __shfl_xor(aw,16);
  ax += __shfl_xor(ax,32); ay += __shfl_xor(ay,32); az += __shfl_xor(az,32); aw += __shfl_xor(aw,32);

  int cc = (lane & 15) << 2;
  float4 bv = ld4(bias_l + cc);
  float h0 = ax*0.25f + bv.x;
  float h1 = ay*0.25f + bv.y;
  float h2v = az*0.25f + bv.z;
  float h3 = aw*0.25f + bv.w;

  float s1 = h0+h1+h2v+h3;
  float s2 = h0*h0 + h1*h1 + h2v*h2v + h3*h3;
  s1 += __shfl_xor(s1,1); s2 += __shfl_xor(s2,1);
  s1 += __shfl_xor(s1,2); s2 += __shfl_xor(s2,2);
  s1 += __shfl_xor(s1,4); s2 += __shfl_xor(s2,4);
  s1 += __shfl_xor(s1,8); s2 += __shfl_xor(s2,8);
  float mu  = s1 * (1.f/64.f);
  float var = fmaxf(s2*(1.f/64.f) - mu*mu, 0.f);
  float rstd = rsqrtf(var + 1e-5f);
  float4 gv  = ld4(g_l + cc);
  float4 bbv = ld4(b_l + cc);
  float r0 = (h0-mu)*rstd*gv.x + bbv.x;
  float r1 = (h1-mu)*rstd*gv.y + bbv.y;
  float r2 = (h2v-mu)*rstd*gv.z + bbv.z;
  float r3 = (h3-mu)*rstd*gv.w + bbv.w;
  if (use_res){
    ushort4 hv = *(const ushort4*)(hbf + (size_t)d*HID + cc);
    r0 += b2f(hv.x); r1 += b2f(hv.y); r2 += b2f(hv.z); r3 += b2f(hv.w);
  }
  if (do_relu){
    r0 = fmaxf(r0, 0.f); r1 = fmaxf(r1, 0.f);
    r2 = fmaxf(r2, 0.f); r3 = fmaxf(r3, 0.f);
  }
  if (lane < 16){
    if (last){
      float4 o = {r0, r1, r2, r3};
      *(float4*)(out_last + (size_t)d*HID + cc) = o;
    } else {
      ushort4 obv = {f2b(r0), f2b(r1), f2b(r2), f2b(r3)};
      *(ushort4*)(hbf + (size_t)d*HID + cc) = obv;
    }
  }
}

// ---------------- launch ----------------
extern "C" void kernel_launch(void* const* d_in, const int* in_sizes, int n_in,
                              void* d_out, int out_size, void* d_ws, size_t ws_size,
                              hipStream_t stream){
  const float* x    = (const float*)d_in[0];
  const int*   ei   = (const int*)d_in[1];
  const int*   ea   = (const int*)d_in[2];
  const float* inW  = (const float*)d_in[3];
  const float* inb  = (const float*)d_in[4];
  const float* etab = (const float*)d_in[5];
  const float* Wl   = (const float*)d_in[6];
  const float* bl   = (const float*)d_in[7];
  const float* Wr   = (const float*)d_in[8];
  const float* br   = (const float*)d_in[9];
  const float* We   = (const float*)d_in[10];
  const float* att  = (const float*)d_in[11];
  const float* ob   = (const float*)d_in[12];
  const float* lg   = (const float*)d_in[13];
  const float* lb   = (const float*)d_in[14];

  char* w = (char*)d_ws;
  size_t off = 0;
  auto alloc = [&](size_t bytes)->char*{
    char* p = w + off;
    off = (off + bytes + 255) & ~(size_t)255;
    return p;
  };
  unsigned short* hbf = (unsigned short*)alloc((size_t)NN*HID*2);
  unsigned short* xlr = (unsigned short*)alloc((size_t)NN*512*2);
  unsigned short* inW_bf = (unsigned short*)alloc((size_t)HID*INDIM*2);
  unsigned short* Wlr    = (unsigned short*)alloc((size_t)NL*512*HID*2);
  float* blr   = (float*)alloc((size_t)NL*512*4);
  float* ep    = (float*)alloc((size_t)NL*3*HC*4);
  int*   deg   = (int*)alloc((size_t)NN*4);
  int*   bsum  = (int*)alloc((size_t)SCAN_NB*4);
  int*   rowp  = (int*)alloc((size_t)(NN+1)*4);
  int*   csrp  = (int*)alloc((size_t)NE*4);
  int*   gbin  = (int*)alloc((size_t)NBIN*BINPAD*4);
  int*   bbase = (int*)alloc((size_t)SCAN_NB*NBIN*4);
  int*   order = (int*)alloc((size_t)NN*4);

  hipMemsetAsync(deg, 0, (size_t)NN*4, stream);

  const int* srcp = ei;
  const int* dstp = ei + NE;
  deg_kernel<<<dim3((NE+255)/256), dim3(256), 0, stream>>>(dstp, deg, gbin);
  scanA_kernel<<<dim3(SCAN_NB), dim3(256), 0, stream>>>(deg, bsum, gbin, bbase);
  scanB_kernel<<<dim3(1), dim3(256), 0, stream>>>(bsum, gbin);
  scanC_kernel<<<dim3(SCAN_NB), dim3(256), 0, stream>>>(deg, bsum, gbin, bbase, rowp, order);
  scatter_kernel<<<dim3((NE+255)/256), dim3(256), 0, stream>>>(srcp, dstp, ea, rowp, deg, csrp);
  prep_kernel<<<dim3(64), dim3(256), 0, stream>>>(inW, Wl, Wr, bl, br, etab, We, inW_bf, Wlr, blr, ep);

  const int MB = (NN + 127)/128;   // 391
  gemm_in_kernel<<<dim3(MB), dim3(256), 0, stream>>>(x, inW_bf, inb, hbf);

  for (int l=0; l<NL; l++){
    gemm_lr_kernel<<<dim3(MB,8), dim3(256), 0, stream>>>(
        hbf, Wlr + (size_t)l*512*HID, blr + (size_t)l*512, xlr);
    agg_kernel<<<dim3((NN+3)/4), dim3(256), 0, stream>>>(
        xlr, rowp, csrp, order,
        ep + (size_t)l*3*HC, att + (size_t)l*HC,
        ob + (size_t)l*HID, lg + (size_t)l*HID, lb + (size_t)l*HID,
        hbf, (float*)d_out,
        (l >= NL/2) ? 1 : 0, (l < NL-1) ? 1 : 0, (l == NL-1) ? 1 : 0);
  }
}

// Round 17
// 492.308 us; speedup vs baseline: 1.1606x; 1.0021x over previous
//
#include <hip/hip_runtime.h>
#include <hip/hip_bf16.h>
#include <hip/hip_fp16.h>
#include <math.h>

#define NN 50000
#define NE 400000
#define INDIM 128
#define HID 64
#define HC 256
#define NL 6
#define ED 16
#define SCAN_B 256
#define SCAN_NB ((NN + SCAN_B - 1)/SCAN_B)   // 196
#define NBIN 64
#define BINPAD 16

typedef __attribute__((ext_vector_type(8))) short short8;
typedef __attribute__((ext_vector_type(4))) float f32x4;
typedef _Float16 h2 __attribute__((ext_vector_type(2)));

static __device__ __forceinline__ float4 ld4(const float* p){ return *(const float4*)p; }
static __device__ __forceinline__ unsigned short f2b(float x){
  __hip_bfloat16 h = __float2bfloat16(x);
  return *(unsigned short*)&h;
}
static __device__ __forceinline__ unsigned short f2h(float x){
  __half h = __float2half(x);
  return *(unsigned short*)&h;
}
static __device__ __forceinline__ float b2f(unsigned short u){
  return __builtin_bit_cast(float, (unsigned)u << 16);
}
static __device__ __forceinline__ h2 bch(unsigned u){ return __builtin_bit_cast(h2, u); }

// DPP lane combine (pure VALU): 0xB1=xor1, 0x4E=xor2, 0x124=row_ror:4, 0x128=row_ror:8
#define DPP_ADD(X, CTRL) \
  ((X) + __builtin_bit_cast(float, __builtin_amdgcn_update_dpp(0, __builtin_bit_cast(int, (X)), (CTRL), 0xF, 0xF, true)))

// ---------------- prep: bf16 weights + Wl/Wr fusion + fp16 ep/att tables ----------------
__global__ void prep_kernel(const float* __restrict__ inW, const float* __restrict__ Wl,
                            const float* __restrict__ Wr, const float* __restrict__ bl,
                            const float* __restrict__ br, const float* __restrict__ etab,
                            const float* __restrict__ We, const float* __restrict__ att,
                            unsigned short* __restrict__ inW_bf,
                            unsigned short* __restrict__ Wlr,
                            float* __restrict__ blr,
                            unsigned short* __restrict__ eph,
                            unsigned short* __restrict__ avh){
  int i = blockIdx.x*blockDim.x + threadIdx.x;
  if (i < HID*INDIM) inW_bf[i] = f2b(inW[i]);
  if (i < NL*512){
    int l = i / 512, c = i % 512;
    blr[i] = (c < HC) ? bl[l*HC + c] : br[l*HC + (c-HC)];
  }
  if (i < NL*3*HC){
    int l  = i / (3*HC);
    int a  = (i / HC) % 3;
    int hc = i % HC;
    const float* wrow = We + ((size_t)l*HC + hc)*ED;
    const float* erow = etab + a*ED;
    float s = 0.f;
    #pragma unroll
    for (int k=0;k<ED;k++) s += erow[k]*wrow[k];
    eph[i] = f2h(s);
  }
  if (i < NL*HC){
    int l = i / HC, c = i % HC;
    const float K6 = 0.6f*1.44269504f, K4 = 0.4f*1.44269504f;
    float a = att[(size_t)l*HC + c];
    avh[(size_t)l*2*HC + c]      = f2h(a*K6);
    avh[(size_t)l*2*HC + HC + c] = f2h(a*K4);
  }
  int tot = NL*512*HID;
  for (int j = i; j < tot; j += gridDim.x*blockDim.x){
    int l = j / (512*HID);
    int c = (j / HID) % 512;
    int k = j % HID;
    float v = (c < HC) ? Wl[((size_t)l*HC + c)*HID + k]
                       : Wr[((size_t)l*HC + (c-HC))*HID + k];
    Wlr[j] = f2b(v);
  }
}

// ---------------- CSR build + degree-sort (fused pre-pass) ----------------
__global__ void deg_kernel(const int* __restrict__ dst, int* __restrict__ deg,
                           int* __restrict__ gbin){
  int e = blockIdx.x*blockDim.x + threadIdx.x;
  if (e < NBIN*BINPAD) gbin[e] = 0;
  if (e < NE) atomicAdd(&deg[dst[e]], 1);
}

__global__ void scanA_kernel(const int* __restrict__ deg, int* __restrict__ bsum,
                             int* __restrict__ gbin, int* __restrict__ bbase){
  __shared__ int lh[NBIN];
  __shared__ int ws[4];
  int t = threadIdx.x, b = blockIdx.x;
  if (t < NBIN) lh[t] = 0;
  __syncthreads();
  int i = b*SCAN_B + t;
  int v = (i < NN) ? deg[i] : 0;
  if (i < NN){
    int dg = v > 63 ? 63 : v;
    atomicAdd(&lh[63 - dg], 1);
  }
  int s = v;
  #pragma unroll
  for (int o=1;o<64;o<<=1) s += __shfl_xor(s,o);
  if ((t&63)==0) ws[t>>6] = s;
  __syncthreads();
  if (t==0) bsum[b] = ws[0]+ws[1]+ws[2]+ws[3];
  if (t < NBIN){
    int c = lh[t];
    bbase[b*NBIN + t] = c ? atomicAdd(&gbin[t*BINPAD], c) : 0;
  }
}

__global__ void scanB_kernel(int* __restrict__ bsum, int* __restrict__ gbin){
  __shared__ int sh[256];
  int t = threadIdx.x;
  int v = (t < SCAN_NB) ? bsum[t] : 0;
  sh[t] = v;
  __syncthreads();
  for (int o=1;o<256;o<<=1){
    int u = (t>=o)?sh[t-o]:0;
    __syncthreads();
    sh[t]+=u;
    __syncthreads();
  }
  int excl = (t==0)?0:sh[t-1];
  if (t < SCAN_NB) bsum[t] = excl;
  if (t < NBIN){
    int v2 = gbin[t*BINPAD];
    int s2 = v2;
    #pragma unroll
    for (int o=1;o<64;o<<=1){
      int u = __shfl_up(s2, o);
      if (t >= o) s2 += u;
    }
    gbin[t*BINPAD] = s2 - v2;
  }
}

__global__ void scanC_kernel(const int* __restrict__ deg, const int* __restrict__ bsum,
                             const int* __restrict__ gbin, const int* __restrict__ bbase,
                             int* __restrict__ rowp, int* __restrict__ order){
  __shared__ int sh[256];
  __shared__ int lc[NBIN];
  int t = threadIdx.x, b = blockIdx.x;
  if (t < NBIN) lc[t] = 0;
  int i = b*SCAN_B + t;
  int v = (i<NN)?deg[i]:0;
  sh[t]=v;
  __syncthreads();
  for (int o=1;o<256;o<<=1){
    int u=(t>=o)?sh[t-o]:0;
    __syncthreads();
    sh[t]+=u;
    __syncthreads();
  }
  if (i < NN) rowp[i] = bsum[b] + sh[t] - v;
  if (i == 0) rowp[NN] = NE;
  if (i < NN){
    int dg = v > 63 ? 63 : v;
    int bin = 63 - dg;
    int r = atomicAdd(&lc[bin], 1);
    order[gbin[bin*BINPAD] + bbase[b*NBIN + bin] + r] = i;
  }
}

__global__ void scatter_kernel(const int* __restrict__ src, const int* __restrict__ dst,
                               const int* __restrict__ attr, const int* __restrict__ rowp,
                               int* __restrict__ deg, int* __restrict__ csrp){
  int e = blockIdx.x*blockDim.x + threadIdx.x;
  if (e >= NE) return;
  int d = dst[e];
  int pos = rowp[d] + atomicSub(&deg[d], 1) - 1;
  csrp[pos] = src[e] | (attr[e] << 16);
}

// ---------------- input GEMM: hbf = bf16(x @ inW.T + b), swapped-operand MFMA ----------------
__global__ __launch_bounds__(256) void gemm_in_kernel(
    const float* __restrict__ X, const unsigned short* __restrict__ Wbf,
    const float* __restrict__ bias, unsigned short* __restrict__ hbf)
{
  int wid = threadIdx.x >> 6, lane = threadIdx.x & 63;
  int row0 = blockIdx.x*128 + wid*32;
  int lr = lane & 15, lk = lane >> 4;
  short8 a[2][4];
  #pragma unroll
  for (int rt=0; rt<2; rt++){
    int r = row0 + rt*16 + lr; if (r >= NN) r = NN-1;
    const float* rp = X + (size_t)r*INDIM;
    #pragma unroll
    for (int ks=0; ks<4; ks++){
      const float* p = rp + ks*32 + lk*8;
      float4 u = ld4(p), v = ld4(p+4);
      short8 t;
      t[0]=(short)f2b(u.x); t[1]=(short)f2b(u.y); t[2]=(short)f2b(u.z); t[3]=(short)f2b(u.w);
      t[4]=(short)f2b(v.x); t[5]=(short)f2b(v.y); t[6]=(short)f2b(v.z); t[7]=(short)f2b(v.w);
      a[rt][ks] = t;
    }
  }
  f32x4 acc[2][4] = {};
  #pragma unroll
  for (int ct=0; ct<4; ct++){
    int c = ct*16 + lr;
    #pragma unroll
    for (int ks=0; ks<4; ks++){
      short8 b = *(const short8*)&Wbf[(size_t)c*INDIM + ks*32 + lk*8];
      #pragma unroll
      for (int rt=0; rt<2; rt++)
        acc[rt][ct] = __builtin_amdgcn_mfma_f32_16x16x32_bf16(b, a[rt][ks], acc[rt][ct], 0,0,0);
    }
  }
  #pragma unroll
  for (int rt=0; rt<2; rt++){
    int r = row0 + rt*16 + lr;
    if (r < NN){
      #pragma unroll
      for (int ct=0; ct<4; ct++){
        int cq = ct*16 + (lk<<2);
        float4 bv = ld4(bias + cq);
        ushort4 o = { f2b(acc[rt][ct][0]+bv.x), f2b(acc[rt][ct][1]+bv.y),
                      f2b(acc[rt][ct][2]+bv.z), f2b(acc[rt][ct][3]+bv.w) };
        *(ushort4*)&hbf[(size_t)r*HID + cq] = o;
      }
    }
  }
}

// ---------------- layer GEMM: xlr = h_bf @ Wlr.T + blr ([NN][512] fp16) ----------------
__global__ __launch_bounds__(256) void gemm_lr_kernel(
    const unsigned short* __restrict__ Abf, const unsigned short* __restrict__ Wbf,
    const float* __restrict__ bias, unsigned short* __restrict__ out)
{
  int wid = threadIdx.x >> 6, lane = threadIdx.x & 63;
  int row0 = blockIdx.x*128 + wid*32;
  int col0 = blockIdx.y*64;
  int lr = lane & 15, lk = lane >> 4;
  short8 a[2][2];
  #pragma unroll
  for (int rt=0; rt<2; rt++){
    int r = row0 + rt*16 + lr; if (r >= NN) r = NN-1;
    #pragma unroll
    for (int ks=0; ks<2; ks++)
      a[rt][ks] = *(const short8*)&Abf[(size_t)r*HID + ks*32 + lk*8];
  }
  f32x4 acc[2][4] = {};
  #pragma unroll
  for (int ct=0; ct<4; ct++){
    int c = col0 + ct*16 + lr;
    #pragma unroll
    for (int ks=0; ks<2; ks++){
      short8 b = *(const short8*)&Wbf[(size_t)c*HID + ks*32 + lk*8];
      #pragma unroll
      for (int rt=0; rt<2; rt++)
        acc[rt][ct] = __builtin_amdgcn_mfma_f32_16x16x32_bf16(b, a[rt][ks], acc[rt][ct], 0,0,0);
    }
  }
  #pragma unroll
  for (int rt=0; rt<2; rt++){
    int r = row0 + rt*16 + lr;
    if (r < NN){
      #pragma unroll
      for (int ct=0; ct<4; ct++){
        int cq = col0 + ct*16 + (lk<<2);
        float4 bv = ld4(bias + cq);
        unsigned lo = (unsigned)f2h(acc[rt][ct][0]+bv.x) | ((unsigned)f2h(acc[rt][ct][1]+bv.y)<<16);
        unsigned hi = (unsigned)f2h(acc[rt][ct][2]+bv.z) | ((unsigned)f2h(acc[rt][ct][3]+bv.w)<<16);
        uint2 o = {lo, hi};
        *(uint2*)&out[(size_t)r*512 + cq] = o;
      }
    }
  }
}

// ---------------- fused GATv2 aggregation + head-mean + LN + residual + relu ----------------
// round-17: fp16 constant tables (eph/avh precomputed per layer) — prologue is 5 loads +
// 6 pk_add; 2-way split accumulators break the serial fma chain across the 4-wide unroll.
#define EDGE_BODY(UX, UY, A, DEN, ACCA, ACCB)                                  \
  {                                                                            \
    h2 x2a = __builtin_bit_cast(h2, (UX));                                     \
    h2 x2b = __builtin_bit_cast(h2, (UY));                                     \
    h2 m2a = x2a + ((A)==0 ? xre0a : ((A)==1 ? xre1a : xre2a));                \
    h2 m2b = x2b + ((A)==0 ? xre0b : ((A)==1 ? xre1b : xre2b));                \
    h2 n2a = __builtin_bit_cast(h2, __builtin_bit_cast(unsigned, m2a) & 0x7FFF7FFFu); \
    h2 n2b = __builtin_bit_cast(h2, __builtin_bit_cast(unsigned, m2b) & 0x7FFF7FFFu); \
    float part = __builtin_amdgcn_fdot2(m2a, av6a, 0.f, false);                \
    part = __builtin_amdgcn_fdot2(m2b, av6b, part, false);                     \
    part = __builtin_amdgcn_fdot2(n2a, av4a, part, false);                     \
    part = __builtin_amdgcn_fdot2(n2b, av4b, part, false);                     \
    part = DPP_ADD(part, 0xB1);                                                \
    part = DPP_ADD(part, 0x4E);                                                \
    part = DPP_ADD(part, 0x124);                                               \
    part = DPP_ADD(part, 0x128);                                               \
    float p;                                                                   \
    asm("v_exp_f32 %0, %1" : "=v"(p) : "v"(part));                             \
    DEN += p;                                                                  \
    _Float16 ph = (_Float16)p;                                                 \
    h2 ph2 = {ph, ph};                                                         \
    ACCA = x2a * ph2 + ACCA;                                                   \
    ACCB = x2b * ph2 + ACCB;                                                   \
  }

#define GOFF(P) ((((unsigned)(P) & 0xFFFFu) << 9) + (unsigned)cb)

__global__ __launch_bounds__(256) void agg_kernel(
    const unsigned short* __restrict__ xlr,
    const int* __restrict__ rowp, const int* __restrict__ csrp,
    const int* __restrict__ order,
    const unsigned short* __restrict__ eph_l, const unsigned short* __restrict__ avh_l,
    const float* __restrict__ bias_l, const float* __restrict__ g_l, const float* __restrict__ b_l,
    unsigned short* __restrict__ hbf, float* __restrict__ out_last,
    int use_res, int do_relu, int last)
{
  int idx = (blockIdx.x << 2) | (threadIdx.x >> 6);
  int lane = threadIdx.x & 63;
  if (idx >= NN) return;
  int d = __builtin_amdgcn_readfirstlane(order[idx]);
  int cb = lane << 2;

  uint2 xru = *(const uint2*)(xlr + ((unsigned)d << 9) + 256u + (unsigned)cb);
  h2 xr2a = __builtin_bit_cast(h2, xru.x);
  h2 xr2b = __builtin_bit_cast(h2, xru.y);

  uint2 e0u = *(const uint2*)(eph_l + cb);
  uint2 e1u = *(const uint2*)(eph_l + HC + cb);
  uint2 e2u = *(const uint2*)(eph_l + 2*HC + cb);
  h2 xre0a = xr2a + bch(e0u.x), xre0b = xr2b + bch(e0u.y);
  h2 xre1a = xr2a + bch(e1u.x), xre1b = xr2b + bch(e1u.y);
  h2 xre2a = xr2a + bch(e2u.x), xre2b = xr2b + bch(e2u.y);

  uint2 a6u = *(const uint2*)(avh_l + cb);
  uint2 a4u = *(const uint2*)(avh_l + HC + cb);
  h2 av6a = bch(a6u.x), av6b = bch(a6u.y);
  h2 av4a = bch(a4u.x), av4b = bch(a4u.y);

  float den0 = 0.f, den1 = 0.f;
  h2 acA0 = {(_Float16)0.f, (_Float16)0.f}, acB0 = {(_Float16)0.f, (_Float16)0.f};
  h2 acA1 = {(_Float16)0.f, (_Float16)0.f}, acB1 = {(_Float16)0.f, (_Float16)0.f};

  int beg = __builtin_amdgcn_readfirstlane(rowp[d]);
  int stop = __builtin_amdgcn_readfirstlane(rowp[d+1]);
  int i = beg;
  for (; i + 4 <= stop; i += 4){
    int p0 = __builtin_amdgcn_readfirstlane(csrp[i]);
    int p1 = __builtin_amdgcn_readfirstlane(csrp[i+1]);
    int p2 = __builtin_amdgcn_readfirstlane(csrp[i+2]);
    int p3 = __builtin_amdgcn_readfirstlane(csrp[i+3]);
    uint2 u0 = *(const uint2*)(xlr + GOFF(p0));
    uint2 u1 = *(const uint2*)(xlr + GOFF(p1));
    uint2 u2 = *(const uint2*)(xlr + GOFF(p2));
    uint2 u3 = *(const uint2*)(xlr + GOFF(p3));
    int a0 = p0 >> 16, a1 = p1 >> 16, a2 = p2 >> 16, a3 = p3 >> 16;
    EDGE_BODY(u0.x, u0.y, a0, den0, acA0, acB0);
    EDGE_BODY(u1.x, u1.y, a1, den1, acA1, acB1);
    EDGE_BODY(u2.x, u2.y, a2, den0, acA0, acB0);
    EDGE_BODY(u3.x, u3.y, a3, den1, acA1, acB1);
  }
  if (i + 2 <= stop){
    int p0 = __builtin_amdgcn_readfirstlane(csrp[i]);
    int p1 = __builtin_amdgcn_readfirstlane(csrp[i+1]);
    uint2 u0 = *(const uint2*)(xlr + GOFF(p0));
    uint2 u1 = *(const uint2*)(xlr + GOFF(p1));
    int a0 = p0 >> 16, a1 = p1 >> 16;
    EDGE_BODY(u0.x, u0.y, a0, den0, acA0, acB0);
    EDGE_BODY(u1.x, u1.y, a1, den1, acA1, acB1);
    i += 2;
  }
  if (i < stop){
    int p0 = __builtin_amdgcn_readfirstlane(csrp[i]);
    uint2 u0 = *(const uint2*)(xlr + GOFF(p0));
    int a0 = p0 >> 16;
    EDGE_BODY(u0.x, u0.y, a0, den0, acA0, acB0);
  }

  float den = den0 + den1;
  h2 acc2a = acA0 + acA1;
  h2 acc2b = acB0 + acB1;

  float ax = (float)acc2a.x, ay = (float)acc2a.y;
  float az = (float)acc2b.x, aw = (float)acc2b.y;
  float inv = (den > 0.f) ? 1.f/den : 0.f;
  ax *= inv; ay *= inv; az *= inv; aw *= inv;

  ax += __shfl_xor(ax,16); ay += __shfl_xor(ay,16); az += __shfl_xor(az,16); aw += __shfl_xor(aw,16);
  ax += __shfl_xor(ax,32); ay += __shfl_xor(ay,32); az += __shfl_xor(az,32); aw += __shfl_xor(aw,32);

  int cc = (lane & 15) << 2;
  float4 bv = ld4(bias_l + cc);
  float h0 = ax*0.25f + bv.x;
  float h1 = ay*0.25f + bv.y;
  float h2v = az*0.25f + bv.z;
  float h3 = aw*0.25f + bv.w;

  float s1 = h0+h1+h2v+h3;
  float s2 = h0*h0 + h1*h1 + h2v*h2v + h3*h3;
  s1 += __shfl_xor(s1,1); s2 += __shfl_xor(s2,1);
  s1 += __shfl_xor(s1,2); s2 += __shfl_xor(s2,2);
  s1 += __shfl_xor(s1,4); s2 += __shfl_xor(s2,4);
  s1 += __shfl_xor(s1,8); s2 += __shfl_xor(s2,8);
  float mu  = s1 * (1.f/64.f);
  float var = fmaxf(s2*(1.f/64.f) - mu*mu, 0.f);
  float rstd = rsqrtf(var + 1e-5f);
  float4 gv  = ld4(g_l + cc);
  float4 bbv = ld4(b_l + cc);
  float r0 = (h0-mu)*rstd*gv.x + bbv.x;
  float r1 = (h1-mu)*rstd*gv.y + bbv.y;
  float r2 = (h2v-mu)*rstd*gv.z + bbv.z;
  float r3 = (h3-mu)*rstd*gv.w + bbv.w;
  if (use_res){
    ushort4 hv = *(const ushort4*)(hbf + (size_t)d*HID + cc);
    r0 += b2f(hv.x); r1 += b2f(hv.y); r2 += b2f(hv.z); r3 += b2f(hv.w);
  }
  if (do_relu){
    r0 = fmaxf(r0, 0.f); r1 = fmaxf(r1, 0.f);
    r2 = fmaxf(r2, 0.f); r3 = fmaxf(r3, 0.f);
  }
  if (lane < 16){
    if (last){
      float4 o = {r0, r1, r2, r3};
      *(float4*)(out_last + (size_t)d*HID + cc) = o;
    } else {
      ushort4 obv = {f2b(r0), f2b(r1), f2b(r2), f2b(r3)};
      *(ushort4*)(hbf + (size_t)d*HID + cc) = obv;
    }
  }
}

// ---------------- launch ----------------
extern "C" void kernel_launch(void* const* d_in, const int* in_sizes, int n_in,
                              void* d_out, int out_size, void* d_ws, size_t ws_size,
                              hipStream_t stream){
  const float* x    = (const float*)d_in[0];
  const int*   ei   = (const int*)d_in[1];
  const int*   ea   = (const int*)d_in[2];
  const float* inW  = (const float*)d_in[3];
  const float* inb  = (const float*)d_in[4];
  const float* etab = (const float*)d_in[5];
  const float* Wl   = (const float*)d_in[6];
  const float* bl   = (const float*)d_in[7];
  const float* Wr   = (const float*)d_in[8];
  const float* br   = (const float*)d_in[9];
  const float* We   = (const float*)d_in[10];
  const float* att  = (const float*)d_in[11];
  const float* ob   = (const float*)d_in[12];
  const float* lg   = (const float*)d_in[13];
  const float* lb   = (const float*)d_in[14];

  char* w = (char*)d_ws;
  size_t off = 0;
  auto alloc = [&](size_t bytes)->char*{
    char* p = w + off;
    off = (off + bytes + 255) & ~(size_t)255;
    return p;
  };
  unsigned short* hbf = (unsigned short*)alloc((size_t)NN*HID*2);
  unsigned short* xlr = (unsigned short*)alloc((size_t)NN*512*2);
  unsigned short* inW_bf = (unsigned short*)alloc((size_t)HID*INDIM*2);
  unsigned short* Wlr    = (unsigned short*)alloc((size_t)NL*512*HID*2);
  float* blr   = (float*)alloc((size_t)NL*512*4);
  unsigned short* eph = (unsigned short*)alloc((size_t)NL*3*HC*2);
  unsigned short* avh = (unsigned short*)alloc((size_t)NL*2*HC*2);
  int*   deg   = (int*)alloc((size_t)NN*4);
  int*   bsum  = (int*)alloc((size_t)SCAN_NB*4);
  int*   rowp  = (int*)alloc((size_t)(NN+1)*4);
  int*   csrp  = (int*)alloc((size_t)NE*4);
  int*   gbin  = (int*)alloc((size_t)NBIN*BINPAD*4);
  int*   bbase = (int*)alloc((size_t)SCAN_NB*NBIN*4);
  int*   order = (int*)alloc((size_t)NN*4);

  hipMemsetAsync(deg, 0, (size_t)NN*4, stream);

  const int* srcp = ei;
  const int* dstp = ei + NE;
  deg_kernel<<<dim3((NE+255)/256), dim3(256), 0, stream>>>(dstp, deg, gbin);
  scanA_kernel<<<dim3(SCAN_NB), dim3(256), 0, stream>>>(deg, bsum, gbin, bbase);
  scanB_kernel<<<dim3(1), dim3(256), 0, stream>>>(bsum, gbin);
  scanC_kernel<<<dim3(SCAN_NB), dim3(256), 0, stream>>>(deg, bsum, gbin, bbase, rowp, order);
  scatter_kernel<<<dim3((NE+255)/256), dim3(256), 0, stream>>>(srcp, dstp, ea, rowp, deg, csrp);
  prep_kernel<<<dim3(64), dim3(256), 0, stream>>>(inW, Wl, Wr, bl, br, etab, We, att,
                                                  inW_bf, Wlr, blr, eph, avh);

  const int MB = (NN + 127)/128;   // 391
  gemm_in_kernel<<<dim3(MB), dim3(256), 0, stream>>>(x, inW_bf, inb, hbf);

  for (int l=0; l<NL; l++){
    gemm_lr_kernel<<<dim3(MB,8), dim3(256), 0, stream>>>(
        hbf, Wlr + (size_t)l*512*HID, blr + (size_t)l*512, xlr);
    agg_kernel<<<dim3((NN+3)/4), dim3(256), 0, stream>>>(
        xlr, rowp, csrp, order,
        eph + (size_t)l*3*HC, avh + (size_t)l*2*HC,
        ob + (size_t)l*HID, lg + (size_t)l*HID, lb + (size_t)l*HID,
        hbf, (float*)d_out,
        (l >= NL/2) ? 1 : 0, (l < NL-1) ? 1 : 0, (l == NL-1) ? 1 : 0);
  }
}